// Round 6
// baseline (2036.554 us; speedup 1.0000x reference)
//
#include <hip/hip_runtime.h>
#include <math.h>

#define N_TOK 75264
#define BDIM 16
#define HDIM 56
#define WDIM 84
#define CDIM 256
#define NHEAD 8
#define HWTOK 4704
#define NQ 49

typedef unsigned short u16;
typedef __attribute__((ext_vector_type(8))) short short8;
typedef __attribute__((ext_vector_type(4))) float floatx4;

__device__ __forceinline__ float bf2f(u16 u) {
    return __builtin_bit_cast(float, (unsigned)u << 16);
}
__device__ __forceinline__ u16 f2bf(float f) {
    unsigned u = __builtin_bit_cast(unsigned, f);
    u += 0x7fffu + ((u >> 16) & 1u);           // round-to-nearest-even
    return (u16)(u >> 16);
}
__device__ __forceinline__ float gelu_exact(float v) {
    return 0.5f * v * (1.0f + erff(v * 0.70710678118654752f));
}

// ---------------- weight split+transpose: W[K][N] fp32 -> Wt_hi/lo [N][K] bf16 ----------
__global__ __launch_bounds__(256)
void wsplit_kernel(const float* __restrict__ q, const float* __restrict__ qcut,
                   const float* __restrict__ a, const float* __restrict__ l,
                   const float* __restrict__ kv, const float* __restrict__ efo,
                   const float* __restrict__ eba, const float* __restrict__ proj,
                   const float* __restrict__ proje,
                   u16* __restrict__ dh, u16* __restrict__ dl)
{
    int e = blockIdx.x * 256 + threadIdx.x;    // 524288 total
    const float* src; int N, base, le;
    if (e < 65536)       { src = q;     N = 256; base = 0;      le = e; }
    else if (e < 98304)  { src = qcut;  N = 128; base = 65536;  le = e - 65536; }
    else if (e < 163840) { src = a;     N = 256; base = 98304;  le = e - 98304; }
    else if (e < 229376) { src = l;     N = 256; base = 163840; le = e - 163840; }
    else if (e < 294912) { src = kv;    N = 256; base = 229376; le = e - 229376; }
    else if (e < 311296) { src = efo;   N = 128; base = 294912; le = e - 294912; }
    else if (e < 327680) { src = eba;   N = 128; base = 311296; le = e - 311296; }
    else if (e < 458752) { src = proj;  N = 256; base = 327680; le = e - 327680; }
    else                 { src = proje; N = 128; base = 458752; le = e - 458752; }
    int K = (base >= 327680) ? 512 : ((base >= 294912) ? 128 : 256);
    int k = le / N, n = le & (N - 1);
    float w = src[le];
    u16 h = f2bf(w);
    dh[base + n * K + k] = h;
    dl[base + n * K + k] = f2bf(w - bf2f(h));
}

// ---------------- LayerNorm: fp32 in -> bf16 hi/lo out ----------------
template<int CH>
__global__ __launch_bounds__(256)
void ln_kernel(const float* __restrict__ x, const float* __restrict__ w,
               const float* __restrict__ b, u16* __restrict__ oh, u16* __restrict__ ol)
{
    const int lane = threadIdx.x & 63;
    const int wv = threadIdx.x >> 6;
    const size_t tok = (size_t)blockIdx.x * 4 + wv;
    constexpr int V = CH / 64;
    float v[V];
    float s = 0.f, sq = 0.f;
    if constexpr (CH == 256) {
        float4 t4 = *(const float4*)(x + tok * CH + lane * 4);
        v[0] = t4.x; v[1] = t4.y; v[2] = t4.z; v[3] = t4.w;
    } else {
        float2 t2 = *(const float2*)(x + tok * CH + lane * 2);
        v[0] = t2.x; v[1] = t2.y;
    }
    #pragma unroll
    for (int i = 0; i < V; ++i) { s += v[i]; sq += v[i] * v[i]; }
    #pragma unroll
    for (int off = 32; off > 0; off >>= 1) {
        s += __shfl_xor(s, off);
        sq += __shfl_xor(sq, off);
    }
    const float mean = s * (1.0f / CH);
    const float var = sq * (1.0f / CH) - mean * mean;
    const float rstd = rsqrtf(var + 1e-6f);
    u16 hh[V], ll[V];
    #pragma unroll
    for (int i = 0; i < V; ++i) {
        float o = (v[i] - mean) * rstd * w[lane * V + i] + b[lane * V + i];
        hh[i] = f2bf(o);
        ll[i] = f2bf(o - bf2f(hh[i]));
    }
    if constexpr (CH == 256) {
        ushort4 th = {hh[0], hh[1], hh[2], hh[3]};
        ushort4 tl = {ll[0], ll[1], ll[2], ll[3]};
        *(ushort4*)(oh + tok * CH + lane * 4) = th;
        *(ushort4*)(ol + tok * CH + lane * 4) = tl;
    } else {
        ushort2 th = {hh[0], hh[1]};
        ushort2 tl = {ll[0], ll[1]};
        *(ushort2*)(oh + tok * CH + lane * 2) = th;
        *(ushort2*)(ol + tok * CH + lane * 2) = tl;
    }
}

// ---------------- AdaptiveAvgPool(7,7) over concat(xn,xen) + scl linear (fp32 out) ------
__global__ __launch_bounds__(128)
void pool_scl_kernel(const u16* __restrict__ xnh, const u16* __restrict__ xnl,
                     const u16* __restrict__ xeh, const u16* __restrict__ xel,
                     const float* __restrict__ sclw, const float* __restrict__ sclb,
                     float* __restrict__ m)
{
    __shared__ float pooled[384];
    const int bp = blockIdx.x;           // b*49 + p
    const int b = bp / 49, p = bp % 49;
    const int py = p / 7, px = p % 7;
    const int tid = threadIdx.x;         // 128
    for (int ch = tid; ch < 384; ch += 128) {
        float acc = 0.f;
        for (int i = 0; i < 96; ++i) {
            int y = py * 8 + i / 12, x = px * 12 + i % 12;
            size_t pix = ((size_t)(b * HDIM + y) * WDIM + x);
            if (ch < 256) acc += bf2f(xnh[pix * 256 + ch]) + bf2f(xnl[pix * 256 + ch]);
            else          acc += bf2f(xeh[pix * 128 + ch - 256]) + bf2f(xel[pix * 128 + ch - 256]);
        }
        pooled[ch] = acc * (1.0f / 96.0f);
    }
    __syncthreads();
    float acc = sclb[tid];
    for (int k = 0; k < 384; ++k) acc = fmaf(pooled[k], sclw[k * 128 + tid], acc);
    m[(size_t)bp * 128 + tid] = acc;
}

// ---------------- MFMA bf16x3 GEMM: D = (Ah+Al)(M,K) @ (Bh+Bl)^T(K,N) + bias ------------
// A: [M][K] hi/lo bf16.  B: PRE-TRANSPOSED [N][K] hi/lo bf16 (wsplit output).
// EPI: 0 = store hi/lo; 1 = gelu, store hi/lo; 2 = multiply existing hi/lo, store hi/lo;
//      3 = store fp32 to Df.
#define BK 32
#define PADK 40
template<int EPI>
__global__ __launch_bounds__(256, 2)
void mgemm(const u16* __restrict__ Ah, const u16* __restrict__ Al, int lda,
           const u16* __restrict__ Bh, const u16* __restrict__ Bl, int K,
           const float* __restrict__ bias,
           u16* __restrict__ Dh, u16* __restrict__ Dl,
           float* __restrict__ Df, int ldd)
{
    __shared__ u16 AsH[128 * PADK], AsL[128 * PADK], BsH[128 * PADK], BsL[128 * PADK];
    const int t = threadIdx.x;
    const int m0 = blockIdx.x * 128, n0 = blockIdx.y * 128;
    const int sr = t >> 1;               // staging row 0..127
    const int sk = (t & 1) * 16;         // staging k-offset
    const int lane = t & 63;
    const int w = t >> 6;
    const int wm = w >> 1, wn = w & 1;   // wave 2x2 grid, each 64x64
    const int frow = lane & 15;
    const int fko = (lane >> 4) * 8;

    const u16* pAh = Ah + (size_t)(m0 + sr) * lda + sk;
    const u16* pAl = Al + (size_t)(m0 + sr) * lda + sk;
    const u16* pBh = Bh + (size_t)(n0 + sr) * K + sk;
    const u16* pBl = Bl + (size_t)(n0 + sr) * K + sk;

    int4 rAh0 = *(const int4*)(pAh);     int4 rAh1 = *(const int4*)(pAh + 8);
    int4 rAl0 = *(const int4*)(pAl);     int4 rAl1 = *(const int4*)(pAl + 8);
    int4 rBh0 = *(const int4*)(pBh);     int4 rBh1 = *(const int4*)(pBh + 8);
    int4 rBl0 = *(const int4*)(pBl);     int4 rBl1 = *(const int4*)(pBl + 8);

    floatx4 acc[4][4] = {};

    for (int k0 = 0; k0 < K; k0 += BK) {
        __syncthreads();
        *(int4*)&AsH[sr * PADK + sk] = rAh0;  *(int4*)&AsH[sr * PADK + sk + 8] = rAh1;
        *(int4*)&AsL[sr * PADK + sk] = rAl0;  *(int4*)&AsL[sr * PADK + sk + 8] = rAl1;
        *(int4*)&BsH[sr * PADK + sk] = rBh0;  *(int4*)&BsH[sr * PADK + sk + 8] = rBh1;
        *(int4*)&BsL[sr * PADK + sk] = rBl0;  *(int4*)&BsL[sr * PADK + sk + 8] = rBl1;
        __syncthreads();
        if (k0 + BK < K) {
            rAh0 = *(const int4*)(pAh + k0 + BK);  rAh1 = *(const int4*)(pAh + k0 + BK + 8);
            rAl0 = *(const int4*)(pAl + k0 + BK);  rAl1 = *(const int4*)(pAl + k0 + BK + 8);
            rBh0 = *(const int4*)(pBh + k0 + BK);  rBh1 = *(const int4*)(pBh + k0 + BK + 8);
            rBl0 = *(const int4*)(pBl + k0 + BK);  rBl1 = *(const int4*)(pBl + k0 + BK + 8);
        }
        short8 afh[4], afl[4], bfh[4], bfl[4];
        #pragma unroll
        for (int i = 0; i < 4; ++i) {
            int ar = wm * 64 + i * 16 + frow;
            afh[i] = *(const short8*)&AsH[ar * PADK + fko];
            afl[i] = *(const short8*)&AsL[ar * PADK + fko];
            int bc = wn * 64 + i * 16 + frow;
            bfh[i] = *(const short8*)&BsH[bc * PADK + fko];
            bfl[i] = *(const short8*)&BsL[bc * PADK + fko];
        }
        #pragma unroll
        for (int mt = 0; mt < 4; ++mt)
        #pragma unroll
        for (int nt = 0; nt < 4; ++nt) {
            acc[mt][nt] = __builtin_amdgcn_mfma_f32_16x16x32_bf16(afh[mt], bfh[nt], acc[mt][nt], 0, 0, 0);
            acc[mt][nt] = __builtin_amdgcn_mfma_f32_16x16x32_bf16(afh[mt], bfl[nt], acc[mt][nt], 0, 0, 0);
            acc[mt][nt] = __builtin_amdgcn_mfma_f32_16x16x32_bf16(afl[mt], bfh[nt], acc[mt][nt], 0, 0, 0);
        }
    }

    // epilogue: C/D layout col = lane&15, row = (lane>>4)*4 + i  [m89-verified]
    #pragma unroll
    for (int mt = 0; mt < 4; ++mt)
    #pragma unroll
    for (int nt = 0; nt < 4; ++nt)
    #pragma unroll
    for (int i = 0; i < 4; ++i) {
        int r = m0 + wm * 64 + mt * 16 + (lane >> 4) * 4 + i;
        int c = n0 + wn * 64 + nt * 16 + (lane & 15);
        float v = acc[mt][nt][i] + bias[c];
        size_t off = (size_t)r * ldd + c;
        if constexpr (EPI == 1) v = gelu_exact(v);
        if constexpr (EPI == 2) v *= bf2f(Dh[off]) + bf2f(Dl[off]);
        if constexpr (EPI == 3) {
            Df[off] = v;
        } else {
            u16 h = f2bf(v);
            Dh[off] = h;
            Dl[off] = f2bf(v - bf2f(h));
        }
    }
}

// ---------------- Depthwise 7x7 conv, channels-last, zero pad 3, bf16-pair I/O ----------
template<int C>
__global__ __launch_bounds__(256)
void dwconv7_kernel(const u16* __restrict__ inh, const u16* __restrict__ inl,
                    const float* __restrict__ w, const float* __restrict__ bias,
                    u16* __restrict__ outh, u16* __restrict__ outl)
{
    constexpr int QP = C / 4;
    constexpr int PPI = 256 / QP;
    constexpr int ITERS = 16 / PPI;
    __shared__ float wlds[49 * C];
    for (int idx = threadIdx.x; idx < C * 49; idx += 256) {
        int c = idx / 49, tap = idx % 49;
        wlds[tap * C + c] = w[idx];
    }
    __syncthreads();
    const int q = threadIdx.x % QP;
    const int sp = threadIdx.x / QP;
    const int c = q * 4;
    const int p0 = blockIdx.x * 16;
    float4 bv = *(const float4*)(bias + c);
    for (int it = 0; it < ITERS; ++it) {
        int p = p0 + it * PPI + sp;
        int x = p % WDIM;
        int tmp = p / WDIM;
        int y = tmp % HDIM;
        int b = tmp / HDIM;
        float4 acc = bv;
        for (int ky = 0; ky < 7; ++ky) {
            int yy = y + ky - 3;
            if (yy < 0 || yy >= HDIM) continue;
            const size_t rowoff = ((size_t)(b * HDIM + yy) * WDIM) * C;
            #pragma unroll
            for (int kx = 0; kx < 7; ++kx) {
                int xx = x + kx - 3;
                if (xx < 0 || xx >= WDIM) continue;
                ushort4 ih = *(const ushort4*)(inh + rowoff + (size_t)xx * C + c);
                ushort4 il = *(const ushort4*)(inl + rowoff + (size_t)xx * C + c);
                const float* wp = wlds + (ky * 7 + kx) * C + c;
                acc.x = fmaf(bf2f(ih.x) + bf2f(il.x), wp[0], acc.x);
                acc.y = fmaf(bf2f(ih.y) + bf2f(il.y), wp[1], acc.y);
                acc.z = fmaf(bf2f(ih.z) + bf2f(il.z), wp[2], acc.z);
                acc.w = fmaf(bf2f(ih.w) + bf2f(il.w), wp[3], acc.w);
            }
        }
        u16 h0 = f2bf(acc.x), h1 = f2bf(acc.y), h2 = f2bf(acc.z), h3 = f2bf(acc.w);
        ushort4 oh = {h0, h1, h2, h3};
        ushort4 ol = {f2bf(acc.x - bf2f(h0)), f2bf(acc.y - bf2f(h1)),
                      f2bf(acc.z - bf2f(h2)), f2bf(acc.w - bf2f(h3))};
        *(ushort4*)(outh + (size_t)p * C + c) = oh;
        *(ushort4*)(outl + (size_t)p * C + c) = ol;
    }
}

// ---------------- Fused attention: softmax((0.25 m) k^T) v, one block per (b,h) ---------
__global__ __launch_bounds__(256)
void attn_fused_kernel(const float* __restrict__ m, const u16* __restrict__ kvh,
                       const u16* __restrict__ kvl, float* __restrict__ ao)
{
    constexpr int T = 96;                 // 4704 = 96 * 49
    __shared__ float mq[NQ * 17];
    __shared__ float Ks[T * 16];
    __shared__ float Vs[T * 16];
    __shared__ float St[NQ * 97];
    __shared__ float Osm[NQ * 16];
    __shared__ float rowm[NQ], rowl[NQ], rowscale[NQ], rownewm[NQ];
    const int bh = blockIdx.x;
    const int b = bh >> 3, h = bh & 7;
    const int tid = threadIdx.x;
    for (int i = tid; i < NQ * 16; i += 256) {
        int p = i >> 4, d = i & 15;
        mq[p * 17 + d] = m[((size_t)(b * 49 + p)) * 128 + h * 16 + d] * 0.25f;
        Osm[i] = 0.f;
    }
    if (tid < NQ) { rowm[tid] = -3.4e38f; rowl[tid] = 0.f; }
    __syncthreads();
    for (int t0 = 0; t0 < HWTOK; t0 += T) {
        for (int i = tid; i < T * 4; i += 256) {
            int row = i >> 2, q = (i & 3) << 2;
            size_t base = ((size_t)(b * HWTOK + t0 + row)) * 256 + h * 16 + q;
            ushort4 kh = *(const ushort4*)(kvh + base);
            ushort4 kl = *(const ushort4*)(kvl + base);
            ushort4 vh = *(const ushort4*)(kvh + base + 128);
            ushort4 vl = *(const ushort4*)(kvl + base + 128);
            Ks[row * 16 + q + 0] = bf2f(kh.x) + bf2f(kl.x);
            Ks[row * 16 + q + 1] = bf2f(kh.y) + bf2f(kl.y);
            Ks[row * 16 + q + 2] = bf2f(kh.z) + bf2f(kl.z);
            Ks[row * 16 + q + 3] = bf2f(kh.w) + bf2f(kl.w);
            Vs[row * 16 + q + 0] = bf2f(vh.x) + bf2f(vl.x);
            Vs[row * 16 + q + 1] = bf2f(vh.y) + bf2f(vl.y);
            Vs[row * 16 + q + 2] = bf2f(vh.z) + bf2f(vl.z);
            Vs[row * 16 + q + 3] = bf2f(vh.w) + bf2f(vl.w);
        }
        __syncthreads();
        for (int i = tid; i < NQ * T; i += 256) {
            int p = i % NQ, t = i / NQ;
            const float* mp = &mq[p * 17];
            const float* kp = &Ks[t * 16];
            float s = 0.f;
            #pragma unroll
            for (int d = 0; d < 16; ++d) s = fmaf(mp[d], kp[d], s);
            St[p * 97 + t] = s;
        }
        __syncthreads();
        if (tid < NQ) {
            float mx = -3.4e38f;
            const float* sr = &St[tid * 97];
            for (int t = 0; t < T; ++t) mx = fmaxf(mx, sr[t]);
            float nm = fmaxf(rowm[tid], mx);
            rownewm[tid] = nm;
            rowscale[tid] = expf(rowm[tid] - nm);
        }
        __syncthreads();
        for (int i = tid; i < NQ * T; i += 256) {
            int p = i / T, t = i % T;
            St[p * 97 + t] = expf(St[p * 97 + t] - rownewm[p]);
        }
        __syncthreads();
        if (tid < NQ) {
            float s = 0.f;
            const float* sr = &St[tid * 97];
            for (int t = 0; t < T; ++t) s += sr[t];
            rowl[tid] = rowl[tid] * rowscale[tid] + s;
            rowm[tid] = rownewm[tid];
        }
        for (int i = tid; i < NQ * 16; i += 256) {
            int p = i >> 4, d = i & 15;
            float acc = Osm[i] * rowscale[p];
            const float* sr = &St[p * 97];
            const float* vp = &Vs[d];
            #pragma unroll 8
            for (int t = 0; t < T; ++t) acc = fmaf(sr[t], vp[t * 16], acc);
            Osm[i] = acc;
        }
        __syncthreads();
    }
    for (int i = tid; i < NQ * 16; i += 256) {
        int p = i >> 4, d = i & 15;
        ao[((size_t)(b * 49 + p)) * 128 + h * 16 + d] = Osm[i] / rowl[p];
    }
}

// ---------------- bilinear 7x7 -> 56x84, writes cat bf16-pair cols 256..383 -------------
__global__ __launch_bounds__(256)
void resize_kernel(const float* __restrict__ ao, u16* __restrict__ cath,
                   u16* __restrict__ catl)
{
    const int idx = blockIdx.x * 256 + threadIdx.x;   // over N*128
    const int c = idx & 127;
    const int p = idx >> 7;
    const int x = p % WDIM;
    int tmp = p / WDIM;
    const int y = tmp % HDIM;
    const int b = tmp / HDIM;
    float fy = (y + 0.5f) * 0.125f - 0.5f;
    float fx = (x + 0.5f) * (1.0f / 12.0f) - 0.5f;
    float yf = floorf(fy), xf = floorf(fx);
    int y0 = (int)yf, x0 = (int)xf;
    float wy = fy - yf, wx = fx - xf;
    int y1 = y0 + 1 < 6 ? y0 + 1 : 6;
    int x1 = x0 + 1 < 6 ? x0 + 1 : 6;
    y0 = y0 > 0 ? y0 : 0;
    x0 = x0 > 0 ? x0 : 0;
    const float* base = ao + (size_t)b * 49 * 128 + c;
    float v00 = base[(y0 * 7 + x0) * 128], v01 = base[(y0 * 7 + x1) * 128];
    float v10 = base[(y1 * 7 + x0) * 128], v11 = base[(y1 * 7 + x1) * 128];
    float r = (1.f - wy) * ((1.f - wx) * v00 + wx * v01)
            + wy * ((1.f - wx) * v10 + wx * v11);
    u16 h = f2bf(r);
    cath[(size_t)p * 512 + 256 + c] = h;
    catl[(size_t)p * 512 + 256 + c] = f2bf(r - bf2f(h));
}

extern "C" void kernel_launch(void* const* d_in, const int* in_sizes, int n_in,
                              void* d_out, int out_size, void* d_ws, size_t ws_size,
                              hipStream_t stream) {
    const float* x       = (const float*)d_in[0];
    const float* x_e     = (const float*)d_in[1];
    const float* ln_w    = (const float*)d_in[2];
    const float* ln_b    = (const float*)d_in[3];
    const float* lne_w   = (const float*)d_in[4];
    const float* lne_b   = (const float*)d_in[5];
    const float* q_w     = (const float*)d_in[6];
    const float* q_b     = (const float*)d_in[7];
    const float* qcut_w  = (const float*)d_in[8];
    const float* qcut_b  = (const float*)d_in[9];
    const float* a_w     = (const float*)d_in[10];
    const float* a_b     = (const float*)d_in[11];
    const float* l_w     = (const float*)d_in[12];
    const float* l_b     = (const float*)d_in[13];
    const float* conv_w  = (const float*)d_in[14];
    const float* conv_b  = (const float*)d_in[15];
    const float* econv_w = (const float*)d_in[16];
    const float* econv_b = (const float*)d_in[17];
    const float* efore_w = (const float*)d_in[18];
    const float* efore_b = (const float*)d_in[19];
    const float* eback_w = (const float*)d_in[20];
    const float* eback_b = (const float*)d_in[21];
    const float* kv_w    = (const float*)d_in[22];
    const float* kv_b    = (const float*)d_in[23];
    const float* scl_w   = (const float*)d_in[24];
    const float* scl_b   = (const float*)d_in[25];
    const float* proj_w  = (const float*)d_in[26];
    const float* proj_b  = (const float*)d_in[27];
    const float* proje_w = (const float*)d_in[28];
    const float* proje_b = (const float*)d_in[29];

    float* out_x = (float*)d_out;                   // (N,256) fp32
    float* out_e = out_x + (size_t)N_TOK * 256;     // (N,128) fp32

    const size_t NT = N_TOK;

    // d_out doubles as scratch (115,605,504 B, exact fit):
    //   xl pair  (NT*512 u16) = out_x region; later hosts e1 (hi half) / e2 (lo half)
    //   xen pair (NT*256 u16) = out_e region
    // All reads of these regions complete before proj/proje overwrite them.
    u16* doutU = (u16*)d_out;
    u16* xlH  = doutU;                 // NT*256
    u16* xlL  = xlH  + NT * 256;       // NT*256
    u16* xenH = xlL  + NT * 256;       // NT*128
    u16* xenL = xenH + NT * 128;       // NT*128

    // Workspace (~223 MiB):
    u16* ws   = (u16*)d_ws;
    u16* xnH  = ws;                    // NT*256  xn -> conv_out -> kv
    u16* xnL  = xnH  + NT * 256;
    u16* catH = xnL  + NT * 256;       // NT*512
    u16* catL = catH + NT * 512;
    u16* wtH  = catL + NT * 512;       // 524288 split weights (transposed [N][K])
    u16* wtL  = wtH  + 524288;
    float* mbuf = (float*)(wtL + 524288);  // 16*49*128 fp32
    float* aosm = mbuf + 16 * 49 * 128;    // 16*49*128 fp32

    // split-weight offsets (must match wsplit_kernel)
    u16 *qtH = wtH + 0,      *qtL = wtL + 0;
    u16 *qctH = wtH + 65536, *qctL = wtL + 65536;
    u16 *atH = wtH + 98304,  *atL = wtL + 98304;
    u16 *ltH = wtH + 163840, *ltL = wtL + 163840;
    u16 *kvtH = wtH + 229376,*kvtL = wtL + 229376;
    u16 *efH = wtH + 294912, *efL = wtL + 294912;
    u16 *ebH = wtH + 311296, *ebL = wtL + 311296;
    u16 *pjH = wtH + 327680, *pjL = wtL + 327680;
    u16 *peH = wtH + 458752, *peL = wtL + 458752;

    // aliases
    u16 *cvH = xnH, *cvL = xnL;        // conv output (after xn dead)
    u16 *kvH = xnH, *kvL = xnL;        // kv (after conv_out dead)
    u16 *e1H = xlH, *e1L = xlH + NT * 128;   // depth branch, in dead xl region
    u16 *e2H = xlL, *e2L = xlL + NT * 128;

    dim3 g2(588, 2), g1(588, 1);

    wsplit_kernel<<<2048, 256, 0, stream>>>(q_w, qcut_w, a_w, l_w, kv_w, efore_w,
                                            eback_w, proj_w, proje_w, wtH, wtL);

    ln_kernel<256><<<N_TOK / 4, 256, 0, stream>>>(x, ln_w, ln_b, xnH, xnL);
    ln_kernel<128><<<N_TOK / 4, 256, 0, stream>>>(x_e, lne_w, lne_b, xenH, xenL);
    pool_scl_kernel<<<16 * 49, 128, 0, stream>>>(xnH, xnL, xenH, xenL, scl_w, scl_b, mbuf);

    mgemm<0><<<g2, 256, 0, stream>>>(xnH, xnL, 256, qtH, qtL, 256, q_b,
                                     catH, catL, nullptr, 512);
    mgemm<0><<<g1, 256, 0, stream>>>(xnH, xnL, 256, qctH, qctL, 256, qcut_b,
                                     catH + 384, catL + 384, nullptr, 512);
    mgemm<1><<<g2, 256, 0, stream>>>(xnH, xnL, 256, ltH, ltL, 256, l_b,
                                     xlH, xlL, nullptr, 256);
    // xn dead
    dwconv7_kernel<256><<<N_TOK / 16, 256, 0, stream>>>(xlH, xlL, conv_w, conv_b, cvH, cvL);
    mgemm<2><<<g2, 256, 0, stream>>>(cvH, cvL, 256, atH, atL, 256, a_b,
                                     catH, catL, nullptr, 512);
    // conv_out dead
    mgemm<0><<<g2, 256, 0, stream>>>(xlH, xlL, 256, kvtH, kvtL, 256, kv_b,
                                     kvH, kvL, nullptr, 256);
    // xl dead -> region hosts e1/e2
    attn_fused_kernel<<<BDIM * NHEAD, 256, 0, stream>>>(mbuf, kvH, kvL, aosm);
    resize_kernel<<<(N_TOK * 128) / 256, 256, 0, stream>>>(aosm, catH, catL);

    mgemm<0><<<g1, 256, 0, stream>>>(xenH, xenL, 128, efH, efL, 128, efore_b,
                                     e1H, e1L, nullptr, 128);
    dwconv7_kernel<128><<<N_TOK / 16, 256, 0, stream>>>(e1H, e1L, econv_w, econv_b, e2H, e2L);
    mgemm<2><<<g1, 256, 0, stream>>>(e2H, e2L, 128, ebH, ebL, 128, eback_b,
                                     catH + 384, catL + 384, nullptr, 512);
    // xen + e1/e2 dead; proj/proje overwrite d_out fully
    mgemm<3><<<g2, 256, 0, stream>>>(catH, catL, 512, pjH, pjL, 512, proj_b,
                                     nullptr, nullptr, out_x, 256);
    mgemm<3><<<g1, 256, 0, stream>>>(catH, catL, 512, peH, peL, 512, proje_b,
                                     nullptr, nullptr, out_e, 128);
}

// Round 7
// 1613.197 us; speedup vs baseline: 1.2624x; 1.2624x over previous
//
#include <hip/hip_runtime.h>
#include <math.h>

#define N_TOK 75264
#define BDIM 16
#define HDIM 56
#define WDIM 84
#define CDIM 256
#define NHEAD 8
#define HWTOK 4704
#define NQ 49
#define SPLIT 8
#define TOKSPL 588
#define TSUB 84

typedef unsigned short u16;
typedef __attribute__((ext_vector_type(8))) short short8;
typedef __attribute__((ext_vector_type(4))) float floatx4;

__device__ __forceinline__ float bf2f(u16 u) {
    return __builtin_bit_cast(float, (unsigned)u << 16);
}
__device__ __forceinline__ u16 f2bf(float f) {
    unsigned u = __builtin_bit_cast(unsigned, f);
    u += 0x7fffu + ((u >> 16) & 1u);           // round-to-nearest-even
    return (u16)(u >> 16);
}
__device__ __forceinline__ float gelu_exact(float v) {
    return 0.5f * v * (1.0f + erff(v * 0.70710678118654752f));
}

// ---------------- weight split+transpose: W[K][N] fp32 -> Wt_hi/lo [N][K] bf16 ----------
__global__ __launch_bounds__(256)
void wsplit_kernel(const float* __restrict__ q, const float* __restrict__ qcut,
                   const float* __restrict__ a, const float* __restrict__ l,
                   const float* __restrict__ kv, const float* __restrict__ efo,
                   const float* __restrict__ eba, const float* __restrict__ proj,
                   const float* __restrict__ proje,
                   u16* __restrict__ dh, u16* __restrict__ dl)
{
    int e = blockIdx.x * 256 + threadIdx.x;    // 524288 total
    const float* src; int N, base, le;
    if (e < 65536)       { src = q;     N = 256; base = 0;      le = e; }
    else if (e < 98304)  { src = qcut;  N = 128; base = 65536;  le = e - 65536; }
    else if (e < 163840) { src = a;     N = 256; base = 98304;  le = e - 98304; }
    else if (e < 229376) { src = l;     N = 256; base = 163840; le = e - 163840; }
    else if (e < 294912) { src = kv;    N = 256; base = 229376; le = e - 229376; }
    else if (e < 311296) { src = efo;   N = 128; base = 294912; le = e - 294912; }
    else if (e < 327680) { src = eba;   N = 128; base = 311296; le = e - 311296; }
    else if (e < 458752) { src = proj;  N = 256; base = 327680; le = e - 327680; }
    else                 { src = proje; N = 128; base = 458752; le = e - 458752; }
    int K = (base >= 327680) ? 512 : ((base >= 294912) ? 128 : 256);
    int k = le / N, n = le & (N - 1);
    float w = src[le];
    u16 h = f2bf(w);
    dh[base + n * K + k] = h;
    dl[base + n * K + k] = f2bf(w - bf2f(h));
}

// ---------------- LayerNorm: fp32 in -> bf16 hi/lo out ----------------
template<int CH>
__global__ __launch_bounds__(256)
void ln_kernel(const float* __restrict__ x, const float* __restrict__ w,
               const float* __restrict__ b, u16* __restrict__ oh, u16* __restrict__ ol)
{
    const int lane = threadIdx.x & 63;
    const int wv = threadIdx.x >> 6;
    const size_t tok = (size_t)blockIdx.x * 4 + wv;
    constexpr int V = CH / 64;
    float v[V];
    float s = 0.f, sq = 0.f;
    if constexpr (CH == 256) {
        float4 t4 = *(const float4*)(x + tok * CH + lane * 4);
        v[0] = t4.x; v[1] = t4.y; v[2] = t4.z; v[3] = t4.w;
    } else {
        float2 t2 = *(const float2*)(x + tok * CH + lane * 2);
        v[0] = t2.x; v[1] = t2.y;
    }
    #pragma unroll
    for (int i = 0; i < V; ++i) { s += v[i]; sq += v[i] * v[i]; }
    #pragma unroll
    for (int off = 32; off > 0; off >>= 1) {
        s += __shfl_xor(s, off);
        sq += __shfl_xor(sq, off);
    }
    const float mean = s * (1.0f / CH);
    const float var = sq * (1.0f / CH) - mean * mean;
    const float rstd = rsqrtf(var + 1e-6f);
    u16 hh[V], ll[V];
    #pragma unroll
    for (int i = 0; i < V; ++i) {
        float o = (v[i] - mean) * rstd * w[lane * V + i] + b[lane * V + i];
        hh[i] = f2bf(o);
        ll[i] = f2bf(o - bf2f(hh[i]));
    }
    if constexpr (CH == 256) {
        ushort4 th = {hh[0], hh[1], hh[2], hh[3]};
        ushort4 tl = {ll[0], ll[1], ll[2], ll[3]};
        *(ushort4*)(oh + tok * CH + lane * 4) = th;
        *(ushort4*)(ol + tok * CH + lane * 4) = tl;
    } else {
        ushort2 th = {hh[0], hh[1]};
        ushort2 tl = {ll[0], ll[1]};
        *(ushort2*)(oh + tok * CH + lane * 2) = th;
        *(ushort2*)(ol + tok * CH + lane * 2) = tl;
    }
}

// ---------------- AdaptiveAvgPool(7,7) over concat(xn,xen) + scl linear (fp32 out) ------
__global__ __launch_bounds__(128)
void pool_scl_kernel(const u16* __restrict__ xnh, const u16* __restrict__ xnl,
                     const u16* __restrict__ xeh, const u16* __restrict__ xel,
                     const float* __restrict__ sclw, const float* __restrict__ sclb,
                     float* __restrict__ m)
{
    __shared__ float pooled[384];
    const int bp = blockIdx.x;           // b*49 + p
    const int b = bp / 49, p = bp % 49;
    const int py = p / 7, px = p % 7;
    const int tid = threadIdx.x;         // 128
    for (int ch = tid; ch < 384; ch += 128) {
        float acc = 0.f;
        for (int i = 0; i < 96; ++i) {
            int y = py * 8 + i / 12, x = px * 12 + i % 12;
            size_t pix = ((size_t)(b * HDIM + y) * WDIM + x);
            if (ch < 256) acc += bf2f(xnh[pix * 256 + ch]) + bf2f(xnl[pix * 256 + ch]);
            else          acc += bf2f(xeh[pix * 128 + ch - 256]) + bf2f(xel[pix * 128 + ch - 256]);
        }
        pooled[ch] = acc * (1.0f / 96.0f);
    }
    __syncthreads();
    float acc = sclb[tid];
    for (int k = 0; k < 384; ++k) acc = fmaf(pooled[k], sclw[k * 128 + tid], acc);
    m[(size_t)bp * 128 + tid] = acc;
}

// ---------------- MFMA bf16x3 GEMM: D = (Ah+Al)(M,K) @ (Bh+Bl)^T(K,N) + bias ------------
// A: [M][K] hi/lo bf16.  B: PRE-TRANSPOSED [N][K] hi/lo bf16 (wsplit output).
// EPI: 0 = store hi/lo; 1 = gelu, store hi/lo; 2 = multiply existing hi/lo, store hi/lo;
//      3 = store fp32 to Df.
#define BK 32
#define PADK 40
template<int EPI>
__global__ __launch_bounds__(256, 2)
void mgemm(const u16* __restrict__ Ah, const u16* __restrict__ Al, int lda,
           const u16* __restrict__ Bh, const u16* __restrict__ Bl, int K,
           const float* __restrict__ bias,
           u16* __restrict__ Dh, u16* __restrict__ Dl,
           float* __restrict__ Df, int ldd)
{
    __shared__ u16 AsH[128 * PADK], AsL[128 * PADK], BsH[128 * PADK], BsL[128 * PADK];
    const int t = threadIdx.x;
    const int m0 = blockIdx.x * 128, n0 = blockIdx.y * 128;
    const int sr = t >> 1;               // staging row 0..127
    const int sk = (t & 1) * 16;         // staging k-offset
    const int lane = t & 63;
    const int w = t >> 6;
    const int wm = w >> 1, wn = w & 1;   // wave 2x2 grid, each 64x64
    const int frow = lane & 15;
    const int fko = (lane >> 4) * 8;

    const u16* pAh = Ah + (size_t)(m0 + sr) * lda + sk;
    const u16* pAl = Al + (size_t)(m0 + sr) * lda + sk;
    const u16* pBh = Bh + (size_t)(n0 + sr) * K + sk;
    const u16* pBl = Bl + (size_t)(n0 + sr) * K + sk;

    int4 rAh0 = *(const int4*)(pAh);     int4 rAh1 = *(const int4*)(pAh + 8);
    int4 rAl0 = *(const int4*)(pAl);     int4 rAl1 = *(const int4*)(pAl + 8);
    int4 rBh0 = *(const int4*)(pBh);     int4 rBh1 = *(const int4*)(pBh + 8);
    int4 rBl0 = *(const int4*)(pBl);     int4 rBl1 = *(const int4*)(pBl + 8);

    floatx4 acc[4][4] = {};

    for (int k0 = 0; k0 < K; k0 += BK) {
        __syncthreads();
        *(int4*)&AsH[sr * PADK + sk] = rAh0;  *(int4*)&AsH[sr * PADK + sk + 8] = rAh1;
        *(int4*)&AsL[sr * PADK + sk] = rAl0;  *(int4*)&AsL[sr * PADK + sk + 8] = rAl1;
        *(int4*)&BsH[sr * PADK + sk] = rBh0;  *(int4*)&BsH[sr * PADK + sk + 8] = rBh1;
        *(int4*)&BsL[sr * PADK + sk] = rBl0;  *(int4*)&BsL[sr * PADK + sk + 8] = rBl1;
        __syncthreads();
        if (k0 + BK < K) {
            rAh0 = *(const int4*)(pAh + k0 + BK);  rAh1 = *(const int4*)(pAh + k0 + BK + 8);
            rAl0 = *(const int4*)(pAl + k0 + BK);  rAl1 = *(const int4*)(pAl + k0 + BK + 8);
            rBh0 = *(const int4*)(pBh + k0 + BK);  rBh1 = *(const int4*)(pBh + k0 + BK + 8);
            rBl0 = *(const int4*)(pBl + k0 + BK);  rBl1 = *(const int4*)(pBl + k0 + BK + 8);
        }
        short8 afh[4], afl[4], bfh[4], bfl[4];
        #pragma unroll
        for (int i = 0; i < 4; ++i) {
            int ar = wm * 64 + i * 16 + frow;
            afh[i] = *(const short8*)&AsH[ar * PADK + fko];
            afl[i] = *(const short8*)&AsL[ar * PADK + fko];
            int bc = wn * 64 + i * 16 + frow;
            bfh[i] = *(const short8*)&BsH[bc * PADK + fko];
            bfl[i] = *(const short8*)&BsL[bc * PADK + fko];
        }
        #pragma unroll
        for (int mt = 0; mt < 4; ++mt)
        #pragma unroll
        for (int nt = 0; nt < 4; ++nt) {
            acc[mt][nt] = __builtin_amdgcn_mfma_f32_16x16x32_bf16(afh[mt], bfh[nt], acc[mt][nt], 0, 0, 0);
            acc[mt][nt] = __builtin_amdgcn_mfma_f32_16x16x32_bf16(afh[mt], bfl[nt], acc[mt][nt], 0, 0, 0);
            acc[mt][nt] = __builtin_amdgcn_mfma_f32_16x16x32_bf16(afl[mt], bfh[nt], acc[mt][nt], 0, 0, 0);
        }
    }

    // epilogue: C/D layout col = lane&15, row = (lane>>4)*4 + i  [m89-verified]
    #pragma unroll
    for (int mt = 0; mt < 4; ++mt)
    #pragma unroll
    for (int nt = 0; nt < 4; ++nt)
    #pragma unroll
    for (int i = 0; i < 4; ++i) {
        int r = m0 + wm * 64 + mt * 16 + (lane >> 4) * 4 + i;
        int c = n0 + wn * 64 + nt * 16 + (lane & 15);
        float v = acc[mt][nt][i] + bias[c];
        size_t off = (size_t)r * ldd + c;
        if constexpr (EPI == 1) v = gelu_exact(v);
        if constexpr (EPI == 2) v *= bf2f(Dh[off]) + bf2f(Dl[off]);
        if constexpr (EPI == 3) {
            Df[off] = v;
        } else {
            u16 h = f2bf(v);
            Dh[off] = h;
            Dl[off] = f2bf(v - bf2f(h));
        }
    }
}

// ---------------- Depthwise 7x7 conv, channels-last, zero pad 3, bf16-pair I/O ----------
template<int C>
__global__ __launch_bounds__(256)
void dwconv7_kernel(const u16* __restrict__ inh, const u16* __restrict__ inl,
                    const float* __restrict__ w, const float* __restrict__ bias,
                    u16* __restrict__ outh, u16* __restrict__ outl)
{
    constexpr int QP = C / 4;
    constexpr int PPI = 256 / QP;
    constexpr int ITERS = 16 / PPI;
    __shared__ float wlds[49 * C];
    for (int idx = threadIdx.x; idx < C * 49; idx += 256) {
        int c = idx / 49, tap = idx % 49;
        wlds[tap * C + c] = w[idx];
    }
    __syncthreads();
    const int q = threadIdx.x % QP;
    const int sp = threadIdx.x / QP;
    const int c = q * 4;
    const int p0 = blockIdx.x * 16;
    float4 bv = *(const float4*)(bias + c);
    for (int it = 0; it < ITERS; ++it) {
        int p = p0 + it * PPI + sp;
        int x = p % WDIM;
        int tmp = p / WDIM;
        int y = tmp % HDIM;
        int b = tmp / HDIM;
        float4 acc = bv;
        for (int ky = 0; ky < 7; ++ky) {
            int yy = y + ky - 3;
            if (yy < 0 || yy >= HDIM) continue;
            const size_t rowoff = ((size_t)(b * HDIM + yy) * WDIM) * C;
            #pragma unroll
            for (int kx = 0; kx < 7; ++kx) {
                int xx = x + kx - 3;
                if (xx < 0 || xx >= WDIM) continue;
                ushort4 ih = *(const ushort4*)(inh + rowoff + (size_t)xx * C + c);
                ushort4 il = *(const ushort4*)(inl + rowoff + (size_t)xx * C + c);
                const float* wp = wlds + (ky * 7 + kx) * C + c;
                acc.x = fmaf(bf2f(ih.x) + bf2f(il.x), wp[0], acc.x);
                acc.y = fmaf(bf2f(ih.y) + bf2f(il.y), wp[1], acc.y);
                acc.z = fmaf(bf2f(ih.z) + bf2f(il.z), wp[2], acc.z);
                acc.w = fmaf(bf2f(ih.w) + bf2f(il.w), wp[3], acc.w);
            }
        }
        u16 h0 = f2bf(acc.x), h1 = f2bf(acc.y), h2 = f2bf(acc.z), h3 = f2bf(acc.w);
        ushort4 oh = {h0, h1, h2, h3};
        ushort4 ol = {f2bf(acc.x - bf2f(h0)), f2bf(acc.y - bf2f(h1)),
                      f2bf(acc.z - bf2f(h2)), f2bf(acc.w - bf2f(h3))};
        *(ushort4*)(outh + (size_t)p * C + c) = oh;
        *(ushort4*)(outl + (size_t)p * C + c) = ol;
    }
}

// ---------------- Split-KV fused attention, partial pass ----------------
// Grid: 1024 blocks = (b*8+h)*SPLIT + s.  Each handles 588 KV tokens in 7 chunks of 84.
// Writes unnormalized partial O plus per-row (m,l).
__global__ __launch_bounds__(256)
void attn_part_kernel(const float* __restrict__ m, const u16* __restrict__ kvh,
                      const u16* __restrict__ kvl,
                      float* __restrict__ Opart, float* __restrict__ mpart,
                      float* __restrict__ lpart)
{
    __shared__ float mq[NQ * 17];
    __shared__ float Ks[TSUB * 16];
    __shared__ float Vs[TSUB * 16];
    __shared__ float St[NQ * 85];
    __shared__ float Osm[NQ * 16];
    __shared__ float rowm[NQ], rowl[NQ], rowscale[NQ], rownewm[NQ];
    const int blk = blockIdx.x;
    const int bh = blk >> 3, s = blk & 7;
    const int b = bh >> 3, h = bh & 7;
    const int tid = threadIdx.x;
    const int tbase = s * TOKSPL;
    for (int i = tid; i < NQ * 16; i += 256) {
        int p = i >> 4, d = i & 15;
        mq[p * 17 + d] = m[((size_t)(b * 49 + p)) * 128 + h * 16 + d] * 0.25f;
        Osm[i] = 0.f;
    }
    if (tid < NQ) { rowm[tid] = -3.4e38f; rowl[tid] = 0.f; }
    __syncthreads();
    for (int c0 = 0; c0 < TOKSPL; c0 += TSUB) {
        const int t0 = tbase + c0;
        // stage K,V chunk (TSUB x 16 each)
        for (int i = tid; i < TSUB * 4; i += 256) {
            int row = i >> 2, q = (i & 3) << 2;
            size_t base = ((size_t)(b * HWTOK + t0 + row)) * 256 + h * 16 + q;
            ushort4 kh = *(const ushort4*)(kvh + base);
            ushort4 kl = *(const ushort4*)(kvl + base);
            ushort4 vh = *(const ushort4*)(kvh + base + 128);
            ushort4 vl = *(const ushort4*)(kvl + base + 128);
            Ks[row * 16 + q + 0] = bf2f(kh.x) + bf2f(kl.x);
            Ks[row * 16 + q + 1] = bf2f(kh.y) + bf2f(kl.y);
            Ks[row * 16 + q + 2] = bf2f(kh.z) + bf2f(kl.z);
            Ks[row * 16 + q + 3] = bf2f(kh.w) + bf2f(kl.w);
            Vs[row * 16 + q + 0] = bf2f(vh.x) + bf2f(vl.x);
            Vs[row * 16 + q + 1] = bf2f(vh.y) + bf2f(vl.y);
            Vs[row * 16 + q + 2] = bf2f(vh.z) + bf2f(vl.z);
            Vs[row * 16 + q + 3] = bf2f(vh.w) + bf2f(vl.w);
        }
        __syncthreads();
        // S tile
        for (int i = tid; i < NQ * TSUB; i += 256) {
            int p = i % NQ, t = i / NQ;
            const float* mp = &mq[p * 17];
            const float* kp = &Ks[t * 16];
            float sv = 0.f;
            #pragma unroll
            for (int d = 0; d < 16; ++d) sv = fmaf(mp[d], kp[d], sv);
            St[p * 85 + t] = sv;
        }
        __syncthreads();
        if (tid < NQ) {
            float mx = -3.4e38f;
            const float* sr = &St[tid * 85];
            for (int t = 0; t < TSUB; ++t) mx = fmaxf(mx, sr[t]);
            float nm = fmaxf(rowm[tid], mx);
            rownewm[tid] = nm;
            rowscale[tid] = expf(rowm[tid] - nm);
        }
        __syncthreads();
        for (int i = tid; i < NQ * TSUB; i += 256) {
            int p = i / TSUB, t = i % TSUB;
            St[p * 85 + t] = expf(St[p * 85 + t] - rownewm[p]);
        }
        __syncthreads();
        if (tid < NQ) {
            float sv = 0.f;
            const float* sr = &St[tid * 85];
            for (int t = 0; t < TSUB; ++t) sv += sr[t];
            rowl[tid] = rowl[tid] * rowscale[tid] + sv;
            rowm[tid] = rownewm[tid];
        }
        // O update
        for (int i = tid; i < NQ * 16; i += 256) {
            int p = i >> 4, d = i & 15;
            float acc = Osm[i] * rowscale[p];
            const float* sr = &St[p * 85];
            const float* vp = &Vs[d];
            #pragma unroll 6
            for (int t = 0; t < TSUB; ++t) acc = fmaf(sr[t], vp[t * 16], acc);
            Osm[i] = acc;
        }
        __syncthreads();
    }
    for (int i = tid; i < NQ * 16; i += 256)
        Opart[(size_t)blk * (NQ * 16) + i] = Osm[i];
    if (tid < NQ) {
        mpart[blk * NQ + tid] = rowm[tid];
        lpart[blk * NQ + tid] = rowl[tid];
    }
}

// ---------------- combine 8 split partials -> ao ----------------
__global__ __launch_bounds__(256)
void attn_combine_kernel(const float* __restrict__ Opart, const float* __restrict__ mpart,
                         const float* __restrict__ lpart, float* __restrict__ ao)
{
    const int bh = blockIdx.x;
    const int b = bh >> 3, h = bh & 7;
    const int tid = threadIdx.x;
    for (int i = tid; i < NQ * 16; i += 256) {
        int p = i >> 4, d = i & 15;
        float M = -3.4e38f;
        #pragma unroll
        for (int s = 0; s < SPLIT; ++s)
            M = fmaxf(M, mpart[(bh * SPLIT + s) * NQ + p]);
        float sO = 0.f, sl = 0.f;
        #pragma unroll
        for (int s = 0; s < SPLIT; ++s) {
            float e = expf(mpart[(bh * SPLIT + s) * NQ + p] - M);
            sl = fmaf(lpart[(bh * SPLIT + s) * NQ + p], e, sl);
            sO = fmaf(Opart[(size_t)(bh * SPLIT + s) * (NQ * 16) + i], e, sO);
        }
        ao[((size_t)(b * 49 + p)) * 128 + h * 16 + d] = sO / sl;
    }
}

// ---------------- bilinear 7x7 -> 56x84, writes cat bf16-pair cols 256..383 -------------
__global__ __launch_bounds__(256)
void resize_kernel(const float* __restrict__ ao, u16* __restrict__ cath,
                   u16* __restrict__ catl)
{
    const int idx = blockIdx.x * 256 + threadIdx.x;   // over N*128
    const int c = idx & 127;
    const int p = idx >> 7;
    const int x = p % WDIM;
    int tmp = p / WDIM;
    const int y = tmp % HDIM;
    const int b = tmp / HDIM;
    float fy = (y + 0.5f) * 0.125f - 0.5f;
    float fx = (x + 0.5f) * (1.0f / 12.0f) - 0.5f;
    float yf = floorf(fy), xf = floorf(fx);
    int y0 = (int)yf, x0 = (int)xf;
    float wy = fy - yf, wx = fx - xf;
    int y1 = y0 + 1 < 6 ? y0 + 1 : 6;
    int x1 = x0 + 1 < 6 ? x0 + 1 : 6;
    y0 = y0 > 0 ? y0 : 0;
    x0 = x0 > 0 ? x0 : 0;
    const float* base = ao + (size_t)b * 49 * 128 + c;
    float v00 = base[(y0 * 7 + x0) * 128], v01 = base[(y0 * 7 + x1) * 128];
    float v10 = base[(y1 * 7 + x0) * 128], v11 = base[(y1 * 7 + x1) * 128];
    float r = (1.f - wy) * ((1.f - wx) * v00 + wx * v01)
            + wy * ((1.f - wx) * v10 + wx * v11);
    u16 h = f2bf(r);
    cath[(size_t)p * 512 + 256 + c] = h;
    catl[(size_t)p * 512 + 256 + c] = f2bf(r - bf2f(h));
}

extern "C" void kernel_launch(void* const* d_in, const int* in_sizes, int n_in,
                              void* d_out, int out_size, void* d_ws, size_t ws_size,
                              hipStream_t stream) {
    const float* x       = (const float*)d_in[0];
    const float* x_e     = (const float*)d_in[1];
    const float* ln_w    = (const float*)d_in[2];
    const float* ln_b    = (const float*)d_in[3];
    const float* lne_w   = (const float*)d_in[4];
    const float* lne_b   = (const float*)d_in[5];
    const float* q_w     = (const float*)d_in[6];
    const float* q_b     = (const float*)d_in[7];
    const float* qcut_w  = (const float*)d_in[8];
    const float* qcut_b  = (const float*)d_in[9];
    const float* a_w     = (const float*)d_in[10];
    const float* a_b     = (const float*)d_in[11];
    const float* l_w     = (const float*)d_in[12];
    const float* l_b     = (const float*)d_in[13];
    const float* conv_w  = (const float*)d_in[14];
    const float* conv_b  = (const float*)d_in[15];
    const float* econv_w = (const float*)d_in[16];
    const float* econv_b = (const float*)d_in[17];
    const float* efore_w = (const float*)d_in[18];
    const float* efore_b = (const float*)d_in[19];
    const float* eback_w = (const float*)d_in[20];
    const float* eback_b = (const float*)d_in[21];
    const float* kv_w    = (const float*)d_in[22];
    const float* kv_b    = (const float*)d_in[23];
    const float* scl_w   = (const float*)d_in[24];
    const float* scl_b   = (const float*)d_in[25];
    const float* proj_w  = (const float*)d_in[26];
    const float* proj_b  = (const float*)d_in[27];
    const float* proje_w = (const float*)d_in[28];
    const float* proje_b = (const float*)d_in[29];

    float* out_x = (float*)d_out;                   // (N,256) fp32
    float* out_e = out_x + (size_t)N_TOK * 256;     // (N,128) fp32

    const size_t NT = N_TOK;

    // d_out doubles as scratch (115,605,504 B, exact fit):
    //   xl pair  (NT*512 u16) = out_x region; later hosts e1 (hi half) / e2 (lo half)
    //   xen pair (NT*256 u16) = out_e region
    // All reads of these regions complete before proj/proje overwrite them.
    u16* doutU = (u16*)d_out;
    u16* xlH  = doutU;                 // NT*256
    u16* xlL  = xlH  + NT * 256;       // NT*256
    u16* xenH = xlL  + NT * 256;       // NT*128
    u16* xenL = xenH + NT * 128;       // NT*128

    // Workspace (~227 MiB):
    u16* ws   = (u16*)d_ws;
    u16* xnH  = ws;                    // NT*256  xn -> conv_out -> kv
    u16* xnL  = xnH  + NT * 256;
    u16* catH = xnL  + NT * 256;       // NT*512
    u16* catL = catH + NT * 512;
    u16* wtH  = catL + NT * 512;       // 524288 split weights (transposed [N][K])
    u16* wtL  = wtH  + 524288;
    float* mbuf  = (float*)(wtL + 524288); // 16*49*128 fp32
    float* aosm  = mbuf + 16 * 49 * 128;   // 16*49*128 fp32
    float* Opart = aosm + 16 * 49 * 128;   // 1024*784 fp32
    float* mpart = Opart + 1024 * NQ * 16; // 1024*49
    float* lpart = mpart + 1024 * NQ;      // 1024*49

    // split-weight offsets (must match wsplit_kernel)
    u16 *qtH = wtH + 0,      *qtL = wtL + 0;
    u16 *qctH = wtH + 65536, *qctL = wtL + 65536;
    u16 *atH = wtH + 98304,  *atL = wtL + 98304;
    u16 *ltH = wtH + 163840, *ltL = wtL + 163840;
    u16 *kvtH = wtH + 229376,*kvtL = wtL + 229376;
    u16 *efH = wtH + 294912, *efL = wtL + 294912;
    u16 *ebH = wtH + 311296, *ebL = wtL + 311296;
    u16 *pjH = wtH + 327680, *pjL = wtL + 327680;
    u16 *peH = wtH + 458752, *peL = wtL + 458752;

    // aliases
    u16 *cvH = xnH, *cvL = xnL;        // conv output (after xn dead)
    u16 *kvH = xnH, *kvL = xnL;        // kv (after conv_out dead)
    u16 *e1H = xlH, *e1L = xlH + NT * 128;   // depth branch, in dead xl region
    u16 *e2H = xlL, *e2L = xlL + NT * 128;

    dim3 g2(588, 2), g1(588, 1);

    wsplit_kernel<<<2048, 256, 0, stream>>>(q_w, qcut_w, a_w, l_w, kv_w, efore_w,
                                            eback_w, proj_w, proje_w, wtH, wtL);

    ln_kernel<256><<<N_TOK / 4, 256, 0, stream>>>(x, ln_w, ln_b, xnH, xnL);
    ln_kernel<128><<<N_TOK / 4, 256, 0, stream>>>(x_e, lne_w, lne_b, xenH, xenL);
    pool_scl_kernel<<<16 * 49, 128, 0, stream>>>(xnH, xnL, xenH, xenL, scl_w, scl_b, mbuf);

    mgemm<0><<<g2, 256, 0, stream>>>(xnH, xnL, 256, qtH, qtL, 256, q_b,
                                     catH, catL, nullptr, 512);
    mgemm<0><<<g1, 256, 0, stream>>>(xnH, xnL, 256, qctH, qctL, 256, qcut_b,
                                     catH + 384, catL + 384, nullptr, 512);
    mgemm<1><<<g2, 256, 0, stream>>>(xnH, xnL, 256, ltH, ltL, 256, l_b,
                                     xlH, xlL, nullptr, 256);
    // xn dead
    dwconv7_kernel<256><<<N_TOK / 16, 256, 0, stream>>>(xlH, xlL, conv_w, conv_b, cvH, cvL);
    mgemm<2><<<g2, 256, 0, stream>>>(cvH, cvL, 256, atH, atL, 256, a_b,
                                     catH, catL, nullptr, 512);
    // conv_out dead
    mgemm<0><<<g2, 256, 0, stream>>>(xlH, xlL, 256, kvtH, kvtL, 256, kv_b,
                                     kvH, kvL, nullptr, 256);
    // xl dead -> region hosts e1/e2
    attn_part_kernel<<<BDIM * NHEAD * SPLIT, 256, 0, stream>>>(mbuf, kvH, kvL,
                                                               Opart, mpart, lpart);
    attn_combine_kernel<<<BDIM * NHEAD, 256, 0, stream>>>(Opart, mpart, lpart, aosm);
    resize_kernel<<<(N_TOK * 128) / 256, 256, 0, stream>>>(aosm, catH, catL);

    mgemm<0><<<g1, 256, 0, stream>>>(xenH, xenL, 128, efH, efL, 128, efore_b,
                                     e1H, e1L, nullptr, 128);
    dwconv7_kernel<128><<<N_TOK / 16, 256, 0, stream>>>(e1H, e1L, econv_w, econv_b, e2H, e2L);
    mgemm<2><<<g1, 256, 0, stream>>>(e2H, e2L, 128, ebH, ebL, 128, eback_b,
                                     catH + 384, catL + 384, nullptr, 512);
    // xen + e1/e2 dead; proj/proje overwrite d_out fully
    mgemm<3><<<g2, 256, 0, stream>>>(catH, catL, 512, pjH, pjL, 512, proj_b,
                                     nullptr, nullptr, out_x, 256);
    mgemm<3><<<g1, 256, 0, stream>>>(catH, catL, 512, peH, peL, 512, proje_b,
                                     nullptr, nullptr, out_e, 128);
}

// Round 8
// 1358.082 us; speedup vs baseline: 1.4996x; 1.1878x over previous
//
#include <hip/hip_runtime.h>
#include <math.h>

#define N_TOK 75264
#define BDIM 16
#define HDIM 56
#define WDIM 84
#define CDIM 256
#define NHEAD 8
#define HWTOK 4704
#define NQ 49
#define SPLIT 8
#define TOKSPL 588
#define TSUB 84

typedef unsigned short u16;
typedef __attribute__((ext_vector_type(8))) short short8;
typedef __attribute__((ext_vector_type(8))) unsigned short ushort8;
typedef __attribute__((ext_vector_type(4))) float floatx4;

__device__ __forceinline__ float bf2f(u16 u) {
    return __builtin_bit_cast(float, (unsigned)u << 16);
}
__device__ __forceinline__ u16 f2bf(float f) {
    unsigned u = __builtin_bit_cast(unsigned, f);
    u += 0x7fffu + ((u >> 16) & 1u);           // round-to-nearest-even
    return (u16)(u >> 16);
}
__device__ __forceinline__ float gelu_exact(float v) {
    return 0.5f * v * (1.0f + erff(v * 0.70710678118654752f));
}

// ---------------- weight split+transpose: W[K][N] fp32 -> Wt_hi/lo [N][K] bf16 ----------
__global__ __launch_bounds__(256)
void wsplit_kernel(const float* __restrict__ q, const float* __restrict__ qcut,
                   const float* __restrict__ a, const float* __restrict__ l,
                   const float* __restrict__ kv, const float* __restrict__ efo,
                   const float* __restrict__ eba, const float* __restrict__ proj,
                   const float* __restrict__ proje,
                   u16* __restrict__ dh, u16* __restrict__ dl)
{
    int e = blockIdx.x * 256 + threadIdx.x;    // 524288 total
    const float* src; int N, base, le;
    if (e < 65536)       { src = q;     N = 256; base = 0;      le = e; }
    else if (e < 98304)  { src = qcut;  N = 128; base = 65536;  le = e - 65536; }
    else if (e < 163840) { src = a;     N = 256; base = 98304;  le = e - 98304; }
    else if (e < 229376) { src = l;     N = 256; base = 163840; le = e - 163840; }
    else if (e < 294912) { src = kv;    N = 256; base = 229376; le = e - 229376; }
    else if (e < 311296) { src = efo;   N = 128; base = 294912; le = e - 294912; }
    else if (e < 327680) { src = eba;   N = 128; base = 311296; le = e - 311296; }
    else if (e < 458752) { src = proj;  N = 256; base = 327680; le = e - 327680; }
    else                 { src = proje; N = 128; base = 458752; le = e - 458752; }
    int K = (base >= 327680) ? 512 : ((base >= 294912) ? 128 : 256);
    int k = le / N, n = le & (N - 1);
    float w = src[le];
    u16 h = f2bf(w);
    dh[base + n * K + k] = h;
    dl[base + n * K + k] = f2bf(w - bf2f(h));
}

// ---------------- conv weight transpose: [C][49] -> [49][C] fp32 ----------------
__global__ __launch_bounds__(256)
void cwt_kernel(const float* __restrict__ conv_w, const float* __restrict__ econv_w,
                float* __restrict__ wt)
{
    int i = blockIdx.x * 256 + threadIdx.x;
    if (i < 12544) {                    // 256*49
        int c = i / 49, tap = i % 49;
        wt[tap * 256 + c] = conv_w[i];
    } else if (i < 18816) {             // + 128*49
        int j = i - 12544;
        int c = j / 49, tap = j % 49;
        wt[12544 + tap * 128 + c] = econv_w[j];
    }
}

// ---------------- LayerNorm: fp32 in -> bf16 hi/lo out ----------------
template<int CH>
__global__ __launch_bounds__(256)
void ln_kernel(const float* __restrict__ x, const float* __restrict__ w,
               const float* __restrict__ b, u16* __restrict__ oh, u16* __restrict__ ol)
{
    const int lane = threadIdx.x & 63;
    const int wv = threadIdx.x >> 6;
    const size_t tok = (size_t)blockIdx.x * 4 + wv;
    constexpr int V = CH / 64;
    float v[V];
    float s = 0.f, sq = 0.f;
    if constexpr (CH == 256) {
        float4 t4 = *(const float4*)(x + tok * CH + lane * 4);
        v[0] = t4.x; v[1] = t4.y; v[2] = t4.z; v[3] = t4.w;
    } else {
        float2 t2 = *(const float2*)(x + tok * CH + lane * 2);
        v[0] = t2.x; v[1] = t2.y;
    }
    #pragma unroll
    for (int i = 0; i < V; ++i) { s += v[i]; sq += v[i] * v[i]; }
    #pragma unroll
    for (int off = 32; off > 0; off >>= 1) {
        s += __shfl_xor(s, off);
        sq += __shfl_xor(sq, off);
    }
    const float mean = s * (1.0f / CH);
    const float var = sq * (1.0f / CH) - mean * mean;
    const float rstd = rsqrtf(var + 1e-6f);
    u16 hh[V], ll[V];
    #pragma unroll
    for (int i = 0; i < V; ++i) {
        float o = (v[i] - mean) * rstd * w[lane * V + i] + b[lane * V + i];
        hh[i] = f2bf(o);
        ll[i] = f2bf(o - bf2f(hh[i]));
    }
    if constexpr (CH == 256) {
        ushort4 th = {hh[0], hh[1], hh[2], hh[3]};
        ushort4 tl = {ll[0], ll[1], ll[2], ll[3]};
        *(ushort4*)(oh + tok * CH + lane * 4) = th;
        *(ushort4*)(ol + tok * CH + lane * 4) = tl;
    } else {
        ushort2 th = {hh[0], hh[1]};
        ushort2 tl = {ll[0], ll[1]};
        *(ushort2*)(oh + tok * CH + lane * 2) = th;
        *(ushort2*)(ol + tok * CH + lane * 2) = tl;
    }
}

// ---------------- AdaptiveAvgPool(7,7) over concat(xn,xen) + scl linear (fp32 out) ------
__global__ __launch_bounds__(128)
void pool_scl_kernel(const u16* __restrict__ xnh, const u16* __restrict__ xnl,
                     const u16* __restrict__ xeh, const u16* __restrict__ xel,
                     const float* __restrict__ sclw, const float* __restrict__ sclb,
                     float* __restrict__ m)
{
    __shared__ float pooled[384];
    const int bp = blockIdx.x;           // b*49 + p
    const int b = bp / 49, p = bp % 49;
    const int py = p / 7, px = p % 7;
    const int tid = threadIdx.x;         // 128
    for (int ch = tid; ch < 384; ch += 128) {
        float acc = 0.f;
        for (int i = 0; i < 96; ++i) {
            int y = py * 8 + i / 12, x = px * 12 + i % 12;
            size_t pix = ((size_t)(b * HDIM + y) * WDIM + x);
            if (ch < 256) acc += bf2f(xnh[pix * 256 + ch]) + bf2f(xnl[pix * 256 + ch]);
            else          acc += bf2f(xeh[pix * 128 + ch - 256]) + bf2f(xel[pix * 128 + ch - 256]);
        }
        pooled[ch] = acc * (1.0f / 96.0f);
    }
    __syncthreads();
    float acc = sclb[tid];
    for (int k = 0; k < 384; ++k) acc = fmaf(pooled[k], sclw[k * 128 + tid], acc);
    m[(size_t)bp * 128 + tid] = acc;
}

// ---------------- MFMA bf16x3 GEMM: D = (Ah+Al)(M,K) @ (Bh+Bl)^T(K,N) + bias ------------
// A: [M][K] hi/lo bf16.  B: PRE-TRANSPOSED [N][K] hi/lo bf16 (wsplit output).
// EPI: 0 = store hi/lo; 1 = gelu, store hi/lo; 2 = multiply existing hi/lo, store hi/lo;
//      3 = store fp32 to Df.
#define BK 32
#define PADK 40
template<int EPI>
__global__ __launch_bounds__(256, 2)
void mgemm(const u16* __restrict__ Ah, const u16* __restrict__ Al, int lda,
           const u16* __restrict__ Bh, const u16* __restrict__ Bl, int K,
           const float* __restrict__ bias,
           u16* __restrict__ Dh, u16* __restrict__ Dl,
           float* __restrict__ Df, int ldd)
{
    __shared__ u16 AsH[128 * PADK], AsL[128 * PADK], BsH[128 * PADK], BsL[128 * PADK];
    const int t = threadIdx.x;
    const int m0 = blockIdx.x * 128, n0 = blockIdx.y * 128;
    const int sr = t >> 1;               // staging row 0..127
    const int sk = (t & 1) * 16;         // staging k-offset
    const int lane = t & 63;
    const int w = t >> 6;
    const int wm = w >> 1, wn = w & 1;   // wave 2x2 grid, each 64x64
    const int frow = lane & 15;
    const int fko = (lane >> 4) * 8;

    const u16* pAh = Ah + (size_t)(m0 + sr) * lda + sk;
    const u16* pAl = Al + (size_t)(m0 + sr) * lda + sk;
    const u16* pBh = Bh + (size_t)(n0 + sr) * K + sk;
    const u16* pBl = Bl + (size_t)(n0 + sr) * K + sk;

    int4 rAh0 = *(const int4*)(pAh);     int4 rAh1 = *(const int4*)(pAh + 8);
    int4 rAl0 = *(const int4*)(pAl);     int4 rAl1 = *(const int4*)(pAl + 8);
    int4 rBh0 = *(const int4*)(pBh);     int4 rBh1 = *(const int4*)(pBh + 8);
    int4 rBl0 = *(const int4*)(pBl);     int4 rBl1 = *(const int4*)(pBl + 8);

    floatx4 acc[4][4] = {};

    for (int k0 = 0; k0 < K; k0 += BK) {
        __syncthreads();
        *(int4*)&AsH[sr * PADK + sk] = rAh0;  *(int4*)&AsH[sr * PADK + sk + 8] = rAh1;
        *(int4*)&AsL[sr * PADK + sk] = rAl0;  *(int4*)&AsL[sr * PADK + sk + 8] = rAl1;
        *(int4*)&BsH[sr * PADK + sk] = rBh0;  *(int4*)&BsH[sr * PADK + sk + 8] = rBh1;
        *(int4*)&BsL[sr * PADK + sk] = rBl0;  *(int4*)&BsL[sr * PADK + sk + 8] = rBl1;
        __syncthreads();
        if (k0 + BK < K) {
            rAh0 = *(const int4*)(pAh + k0 + BK);  rAh1 = *(const int4*)(pAh + k0 + BK + 8);
            rAl0 = *(const int4*)(pAl + k0 + BK);  rAl1 = *(const int4*)(pAl + k0 + BK + 8);
            rBh0 = *(const int4*)(pBh + k0 + BK);  rBh1 = *(const int4*)(pBh + k0 + BK + 8);
            rBl0 = *(const int4*)(pBl + k0 + BK);  rBl1 = *(const int4*)(pBl + k0 + BK + 8);
        }
        short8 afh[4], afl[4], bfh[4], bfl[4];
        #pragma unroll
        for (int i = 0; i < 4; ++i) {
            int ar = wm * 64 + i * 16 + frow;
            afh[i] = *(const short8*)&AsH[ar * PADK + fko];
            afl[i] = *(const short8*)&AsL[ar * PADK + fko];
            int bc = wn * 64 + i * 16 + frow;
            bfh[i] = *(const short8*)&BsH[bc * PADK + fko];
            bfl[i] = *(const short8*)&BsL[bc * PADK + fko];
        }
        #pragma unroll
        for (int mt = 0; mt < 4; ++mt)
        #pragma unroll
        for (int nt = 0; nt < 4; ++nt) {
            acc[mt][nt] = __builtin_amdgcn_mfma_f32_16x16x32_bf16(afh[mt], bfh[nt], acc[mt][nt], 0, 0, 0);
            acc[mt][nt] = __builtin_amdgcn_mfma_f32_16x16x32_bf16(afh[mt], bfl[nt], acc[mt][nt], 0, 0, 0);
            acc[mt][nt] = __builtin_amdgcn_mfma_f32_16x16x32_bf16(afl[mt], bfh[nt], acc[mt][nt], 0, 0, 0);
        }
    }

    // epilogue: C/D layout col = lane&15, row = (lane>>4)*4 + i  [m89-verified]
    #pragma unroll
    for (int mt = 0; mt < 4; ++mt)
    #pragma unroll
    for (int nt = 0; nt < 4; ++nt)
    #pragma unroll
    for (int i = 0; i < 4; ++i) {
        int r = m0 + wm * 64 + mt * 16 + (lane >> 4) * 4 + i;
        int c = n0 + wn * 64 + nt * 16 + (lane & 15);
        float v = acc[mt][nt][i] + bias[c];
        size_t off = (size_t)r * ldd + c;
        if constexpr (EPI == 1) v = gelu_exact(v);
        if constexpr (EPI == 2) v *= bf2f(Dh[off]) + bf2f(Dl[off]);
        if constexpr (EPI == 3) {
            Df[off] = v;
        } else {
            u16 h = f2bf(v);
            Dh[off] = h;
            Dl[off] = f2bf(v - bf2f(h));
        }
    }
}

// ---------------- Depthwise 7x7 conv, channels-last, zero pad 3, bf16-pair I/O ----------
// No LDS: weights read from pre-transposed wT[tap][C] fp32 (L1/L2-resident).
// One thread = one pixel x 8 channels (ushort8 loads).
template<int C>
__global__ __launch_bounds__(256)
void dwconv7_kernel(const u16* __restrict__ inh, const u16* __restrict__ inl,
                    const float* __restrict__ wT, const float* __restrict__ bias,
                    u16* __restrict__ outh, u16* __restrict__ outl)
{
    constexpr int CPW = C / 8;           // channel-octs per pixel
    const int gid = blockIdx.x * 256 + threadIdx.x;   // over N_TOK * CPW
    const int cw = gid & (CPW - 1);
    const int p = gid / CPW;
    const int c = cw * 8;
    const int x = p % WDIM;
    int tmp = p / WDIM;
    const int y = tmp % HDIM;
    const int b = tmp / HDIM;
    float acc[8];
    {
        float4 b0 = *(const float4*)(bias + c);
        float4 b1 = *(const float4*)(bias + c + 4);
        acc[0] = b0.x; acc[1] = b0.y; acc[2] = b0.z; acc[3] = b0.w;
        acc[4] = b1.x; acc[5] = b1.y; acc[6] = b1.z; acc[7] = b1.w;
    }
    for (int ky = 0; ky < 7; ++ky) {
        int yy = y + ky - 3;
        if (yy < 0 || yy >= HDIM) continue;
        const size_t rowoff = ((size_t)(b * HDIM + yy) * WDIM) * C;
        #pragma unroll
        for (int kx = 0; kx < 7; ++kx) {
            int xx = x + kx - 3;
            if (xx < 0 || xx >= WDIM) continue;
            ushort8 ih = *(const ushort8*)(inh + rowoff + (size_t)xx * C + c);
            ushort8 il = *(const ushort8*)(inl + rowoff + (size_t)xx * C + c);
            const float* wp = wT + (ky * 7 + kx) * C + c;
            float4 w0 = *(const float4*)(wp);
            float4 w1 = *(const float4*)(wp + 4);
            acc[0] = fmaf(bf2f(ih[0]) + bf2f(il[0]), w0.x, acc[0]);
            acc[1] = fmaf(bf2f(ih[1]) + bf2f(il[1]), w0.y, acc[1]);
            acc[2] = fmaf(bf2f(ih[2]) + bf2f(il[2]), w0.z, acc[2]);
            acc[3] = fmaf(bf2f(ih[3]) + bf2f(il[3]), w0.w, acc[3]);
            acc[4] = fmaf(bf2f(ih[4]) + bf2f(il[4]), w1.x, acc[4]);
            acc[5] = fmaf(bf2f(ih[5]) + bf2f(il[5]), w1.y, acc[5]);
            acc[6] = fmaf(bf2f(ih[6]) + bf2f(il[6]), w1.z, acc[6]);
            acc[7] = fmaf(bf2f(ih[7]) + bf2f(il[7]), w1.w, acc[7]);
        }
    }
    ushort8 oh, ol;
    #pragma unroll
    for (int j = 0; j < 8; ++j) {
        u16 h = f2bf(acc[j]);
        oh[j] = h;
        ol[j] = f2bf(acc[j] - bf2f(h));
    }
    *(ushort8*)(outh + (size_t)p * C + c) = oh;
    *(ushort8*)(outl + (size_t)p * C + c) = ol;
}

// ---------------- Split-KV fused attention, partial pass ----------------
// Grid: 1024 blocks = (b*8+h)*SPLIT + s.  Each handles 588 KV tokens in 7 chunks of 84.
// Writes unnormalized partial O plus per-row (m,l).
__global__ __launch_bounds__(256)
void attn_part_kernel(const float* __restrict__ m, const u16* __restrict__ kvh,
                      const u16* __restrict__ kvl,
                      float* __restrict__ Opart, float* __restrict__ mpart,
                      float* __restrict__ lpart)
{
    __shared__ float mq[NQ * 17];
    __shared__ float Ks[TSUB * 16];
    __shared__ float Vs[TSUB * 16];
    __shared__ float St[NQ * 85];
    __shared__ float Osm[NQ * 16];
    __shared__ float rowm[NQ], rowl[NQ], rowscale[NQ], rownewm[NQ];
    const int blk = blockIdx.x;
    const int bh = blk >> 3, s = blk & 7;
    const int b = bh >> 3, h = bh & 7;
    const int tid = threadIdx.x;
    const int tbase = s * TOKSPL;
    for (int i = tid; i < NQ * 16; i += 256) {
        int p = i >> 4, d = i & 15;
        mq[p * 17 + d] = m[((size_t)(b * 49 + p)) * 128 + h * 16 + d] * 0.25f;
        Osm[i] = 0.f;
    }
    if (tid < NQ) { rowm[tid] = -3.4e38f; rowl[tid] = 0.f; }
    __syncthreads();
    for (int c0 = 0; c0 < TOKSPL; c0 += TSUB) {
        const int t0 = tbase + c0;
        for (int i = tid; i < TSUB * 4; i += 256) {
            int row = i >> 2, q = (i & 3) << 2;
            size_t base = ((size_t)(b * HWTOK + t0 + row)) * 256 + h * 16 + q;
            ushort4 kh = *(const ushort4*)(kvh + base);
            ushort4 kl = *(const ushort4*)(kvl + base);
            ushort4 vh = *(const ushort4*)(kvh + base + 128);
            ushort4 vl = *(const ushort4*)(kvl + base + 128);
            Ks[row * 16 + q + 0] = bf2f(kh.x) + bf2f(kl.x);
            Ks[row * 16 + q + 1] = bf2f(kh.y) + bf2f(kl.y);
            Ks[row * 16 + q + 2] = bf2f(kh.z) + bf2f(kl.z);
            Ks[row * 16 + q + 3] = bf2f(kh.w) + bf2f(kl.w);
            Vs[row * 16 + q + 0] = bf2f(vh.x) + bf2f(vl.x);
            Vs[row * 16 + q + 1] = bf2f(vh.y) + bf2f(vl.y);
            Vs[row * 16 + q + 2] = bf2f(vh.z) + bf2f(vl.z);
            Vs[row * 16 + q + 3] = bf2f(vh.w) + bf2f(vl.w);
        }
        __syncthreads();
        for (int i = tid; i < NQ * TSUB; i += 256) {
            int p = i % NQ, t = i / NQ;
            const float* mp = &mq[p * 17];
            const float* kp = &Ks[t * 16];
            float sv = 0.f;
            #pragma unroll
            for (int d = 0; d < 16; ++d) sv = fmaf(mp[d], kp[d], sv);
            St[p * 85 + t] = sv;
        }
        __syncthreads();
        if (tid < NQ) {
            float mx = -3.4e38f;
            const float* sr = &St[tid * 85];
            for (int t = 0; t < TSUB; ++t) mx = fmaxf(mx, sr[t]);
            float nm = fmaxf(rowm[tid], mx);
            rownewm[tid] = nm;
            rowscale[tid] = expf(rowm[tid] - nm);
        }
        __syncthreads();
        for (int i = tid; i < NQ * TSUB; i += 256) {
            int p = i / TSUB, t = i % TSUB;
            St[p * 85 + t] = expf(St[p * 85 + t] - rownewm[p]);
        }
        __syncthreads();
        if (tid < NQ) {
            float sv = 0.f;
            const float* sr = &St[tid * 85];
            for (int t = 0; t < TSUB; ++t) sv += sr[t];
            rowl[tid] = rowl[tid] * rowscale[tid] + sv;
            rowm[tid] = rownewm[tid];
        }
        for (int i = tid; i < NQ * 16; i += 256) {
            int p = i >> 4, d = i & 15;
            float acc = Osm[i] * rowscale[p];
            const float* sr = &St[p * 85];
            const float* vp = &Vs[d];
            #pragma unroll 6
            for (int t = 0; t < TSUB; ++t) acc = fmaf(sr[t], vp[t * 16], acc);
            Osm[i] = acc;
        }
        __syncthreads();
    }
    for (int i = tid; i < NQ * 16; i += 256)
        Opart[(size_t)blk * (NQ * 16) + i] = Osm[i];
    if (tid < NQ) {
        mpart[blk * NQ + tid] = rowm[tid];
        lpart[blk * NQ + tid] = rowl[tid];
    }
}

// ---------------- combine 8 split partials -> ao ----------------
__global__ __launch_bounds__(256)
void attn_combine_kernel(const float* __restrict__ Opart, const float* __restrict__ mpart,
                         const float* __restrict__ lpart, float* __restrict__ ao)
{
    const int bh = blockIdx.x;
    const int b = bh >> 3, h = bh & 7;
    const int tid = threadIdx.x;
    for (int i = tid; i < NQ * 16; i += 256) {
        int p = i >> 4, d = i & 15;
        float M = -3.4e38f;
        #pragma unroll
        for (int s = 0; s < SPLIT; ++s)
            M = fmaxf(M, mpart[(bh * SPLIT + s) * NQ + p]);
        float sO = 0.f, sl = 0.f;
        #pragma unroll
        for (int s = 0; s < SPLIT; ++s) {
            float e = expf(mpart[(bh * SPLIT + s) * NQ + p] - M);
            sl = fmaf(lpart[(bh * SPLIT + s) * NQ + p], e, sl);
            sO = fmaf(Opart[(size_t)(bh * SPLIT + s) * (NQ * 16) + i], e, sO);
        }
        ao[((size_t)(b * 49 + p)) * 128 + h * 16 + d] = sO / sl;
    }
}

// ---------------- bilinear 7x7 -> 56x84, writes cat bf16-pair cols 256..383 -------------
__global__ __launch_bounds__(256)
void resize_kernel(const float* __restrict__ ao, u16* __restrict__ cath,
                   u16* __restrict__ catl)
{
    const int idx = blockIdx.x * 256 + threadIdx.x;   // over N*128
    const int c = idx & 127;
    const int p = idx >> 7;
    const int x = p % WDIM;
    int tmp = p / WDIM;
    const int y = tmp % HDIM;
    const int b = tmp / HDIM;
    float fy = (y + 0.5f) * 0.125f - 0.5f;
    float fx = (x + 0.5f) * (1.0f / 12.0f) - 0.5f;
    float yf = floorf(fy), xf = floorf(fx);
    int y0 = (int)yf, x0 = (int)xf;
    float wy = fy - yf, wx = fx - xf;
    int y1 = y0 + 1 < 6 ? y0 + 1 : 6;
    int x1 = x0 + 1 < 6 ? x0 + 1 : 6;
    y0 = y0 > 0 ? y0 : 0;
    x0 = x0 > 0 ? x0 : 0;
    const float* base = ao + (size_t)b * 49 * 128 + c;
    float v00 = base[(y0 * 7 + x0) * 128], v01 = base[(y0 * 7 + x1) * 128];
    float v10 = base[(y1 * 7 + x0) * 128], v11 = base[(y1 * 7 + x1) * 128];
    float r = (1.f - wy) * ((1.f - wx) * v00 + wx * v01)
            + wy * ((1.f - wx) * v10 + wx * v11);
    u16 h = f2bf(r);
    cath[(size_t)p * 512 + 256 + c] = h;
    catl[(size_t)p * 512 + 256 + c] = f2bf(r - bf2f(h));
}

extern "C" void kernel_launch(void* const* d_in, const int* in_sizes, int n_in,
                              void* d_out, int out_size, void* d_ws, size_t ws_size,
                              hipStream_t stream) {
    const float* x       = (const float*)d_in[0];
    const float* x_e     = (const float*)d_in[1];
    const float* ln_w    = (const float*)d_in[2];
    const float* ln_b    = (const float*)d_in[3];
    const float* lne_w   = (const float*)d_in[4];
    const float* lne_b   = (const float*)d_in[5];
    const float* q_w     = (const float*)d_in[6];
    const float* q_b     = (const float*)d_in[7];
    const float* qcut_w  = (const float*)d_in[8];
    const float* qcut_b  = (const float*)d_in[9];
    const float* a_w     = (const float*)d_in[10];
    const float* a_b     = (const float*)d_in[11];
    const float* l_w     = (const float*)d_in[12];
    const float* l_b     = (const float*)d_in[13];
    const float* conv_w  = (const float*)d_in[14];
    const float* conv_b  = (const float*)d_in[15];
    const float* econv_w = (const float*)d_in[16];
    const float* econv_b = (const float*)d_in[17];
    const float* efore_w = (const float*)d_in[18];
    const float* efore_b = (const float*)d_in[19];
    const float* eback_w = (const float*)d_in[20];
    const float* eback_b = (const float*)d_in[21];
    const float* kv_w    = (const float*)d_in[22];
    const float* kv_b    = (const float*)d_in[23];
    const float* scl_w   = (const float*)d_in[24];
    const float* scl_b   = (const float*)d_in[25];
    const float* proj_w  = (const float*)d_in[26];
    const float* proj_b  = (const float*)d_in[27];
    const float* proje_w = (const float*)d_in[28];
    const float* proje_b = (const float*)d_in[29];

    float* out_x = (float*)d_out;                   // (N,256) fp32
    float* out_e = out_x + (size_t)N_TOK * 256;     // (N,128) fp32

    const size_t NT = N_TOK;

    // d_out doubles as scratch (115,605,504 B, exact fit):
    //   xl pair  (NT*512 u16) = out_x region; later hosts e1 (hi half) / e2 (lo half)
    //   xen pair (NT*256 u16) = out_e region
    // All reads of these regions complete before proj/proje overwrite them.
    u16* doutU = (u16*)d_out;
    u16* xlH  = doutU;                 // NT*256
    u16* xlL  = xlH  + NT * 256;       // NT*256
    u16* xenH = xlL  + NT * 256;       // NT*128
    u16* xenL = xenH + NT * 128;       // NT*128

    // Workspace (~227 MiB):
    u16* ws   = (u16*)d_ws;
    u16* xnH  = ws;                    // NT*256  xn -> conv_out -> kv
    u16* xnL  = xnH  + NT * 256;
    u16* catH = xnL  + NT * 256;       // NT*512
    u16* catL = catH + NT * 512;
    u16* wtH  = catL + NT * 512;       // 524288 split weights (transposed [N][K])
    u16* wtL  = wtH  + 524288;
    float* mbuf  = (float*)(wtL + 524288); // 16*49*128 fp32
    float* aosm  = mbuf + 16 * 49 * 128;   // 16*49*128 fp32
    float* Opart = aosm + 16 * 49 * 128;   // 1024*784 fp32
    float* mpart = Opart + 1024 * NQ * 16; // 1024*49
    float* lpart = mpart + 1024 * NQ;      // 1024*49
    float* cwT   = lpart + 1024 * NQ;      // 49*256 + 49*128 fp32 transposed conv weights
    float* ecwT  = cwT + 12544;

    // split-weight offsets (must match wsplit_kernel)
    u16 *qtH = wtH + 0,      *qtL = wtL + 0;
    u16 *qctH = wtH + 65536, *qctL = wtL + 65536;
    u16 *atH = wtH + 98304,  *atL = wtL + 98304;
    u16 *ltH = wtH + 163840, *ltL = wtL + 163840;
    u16 *kvtH = wtH + 229376,*kvtL = wtL + 229376;
    u16 *efH = wtH + 294912, *efL = wtL + 294912;
    u16 *ebH = wtH + 311296, *ebL = wtL + 311296;
    u16 *pjH = wtH + 327680, *pjL = wtL + 327680;
    u16 *peH = wtH + 458752, *peL = wtL + 458752;

    // aliases
    u16 *cvH = xnH, *cvL = xnL;        // conv output (after xn dead)
    u16 *kvH = xnH, *kvL = xnL;        // kv (after conv_out dead)
    u16 *e1H = xlH, *e1L = xlH + NT * 128;   // depth branch, in dead xl region
    u16 *e2H = xlL, *e2L = xlL + NT * 128;

    dim3 g2(588, 2), g1(588, 1);

    wsplit_kernel<<<2048, 256, 0, stream>>>(q_w, qcut_w, a_w, l_w, kv_w, efore_w,
                                            eback_w, proj_w, proje_w, wtH, wtL);
    cwt_kernel<<<74, 256, 0, stream>>>(conv_w, econv_w, cwT);

    ln_kernel<256><<<N_TOK / 4, 256, 0, stream>>>(x, ln_w, ln_b, xnH, xnL);
    ln_kernel<128><<<N_TOK / 4, 256, 0, stream>>>(x_e, lne_w, lne_b, xenH, xenL);
    pool_scl_kernel<<<16 * 49, 128, 0, stream>>>(xnH, xnL, xenH, xenL, scl_w, scl_b, mbuf);

    mgemm<0><<<g2, 256, 0, stream>>>(xnH, xnL, 256, qtH, qtL, 256, q_b,
                                     catH, catL, nullptr, 512);
    mgemm<0><<<g1, 256, 0, stream>>>(xnH, xnL, 256, qctH, qctL, 256, qcut_b,
                                     catH + 384, catL + 384, nullptr, 512);
    mgemm<1><<<g2, 256, 0, stream>>>(xnH, xnL, 256, ltH, ltL, 256, l_b,
                                     xlH, xlL, nullptr, 256);
    // xn dead
    dwconv7_kernel<256><<<(N_TOK * 32) / 256, 256, 0, stream>>>(xlH, xlL, cwT, conv_b, cvH, cvL);
    mgemm<2><<<g2, 256, 0, stream>>>(cvH, cvL, 256, atH, atL, 256, a_b,
                                     catH, catL, nullptr, 512);
    // conv_out dead
    mgemm<0><<<g2, 256, 0, stream>>>(xlH, xlL, 256, kvtH, kvtL, 256, kv_b,
                                     kvH, kvL, nullptr, 256);
    // xl dead -> region hosts e1/e2
    attn_part_kernel<<<BDIM * NHEAD * SPLIT, 256, 0, stream>>>(mbuf, kvH, kvL,
                                                               Opart, mpart, lpart);
    attn_combine_kernel<<<BDIM * NHEAD, 256, 0, stream>>>(Opart, mpart, lpart, aosm);
    resize_kernel<<<(N_TOK * 128) / 256, 256, 0, stream>>>(aosm, catH, catL);

    mgemm<0><<<g1, 256, 0, stream>>>(xenH, xenL, 128, efH, efL, 128, efore_b,
                                     e1H, e1L, nullptr, 128);
    dwconv7_kernel<128><<<(N_TOK * 16) / 256, 256, 0, stream>>>(e1H, e1L, ecwT, econv_b, e2H, e2L);
    mgemm<2><<<g1, 256, 0, stream>>>(e2H, e2L, 128, ebH, ebL, 128, eback_b,
                                     catH + 384, catL + 384, nullptr, 512);
    // xen + e1/e2 dead; proj/proje overwrite d_out fully
    mgemm<3><<<g2, 256, 0, stream>>>(catH, catL, 512, pjH, pjL, 512, proj_b,
                                     nullptr, nullptr, out_x, 256);
    mgemm<3><<<g1, 256, 0, stream>>>(catH, catL, 512, peH, peL, 512, proje_b,
                                     nullptr, nullptr, out_e, 128);
}

// Round 11
// 1351.321 us; speedup vs baseline: 1.5071x; 1.0050x over previous
//
#include <hip/hip_runtime.h>
#include <math.h>

#define N_TOK 75264
#define BDIM 16
#define HDIM 56
#define WDIM 84
#define CDIM 256
#define NHEAD 8
#define HWTOK 4704
#define NQ 49
#define SPLIT 8
#define TOKSPL 588
#define TSUB 84

typedef unsigned short u16;
typedef __attribute__((ext_vector_type(8))) short short8;
typedef __attribute__((ext_vector_type(8))) unsigned short ushort8;
typedef __attribute__((ext_vector_type(4))) float floatx4;

__device__ __forceinline__ float bf2f(u16 u) {
    return __builtin_bit_cast(float, (unsigned)u << 16);
}
__device__ __forceinline__ u16 f2bf(float f) {
    unsigned u = __builtin_bit_cast(unsigned, f);
    u += 0x7fffu + ((u >> 16) & 1u);           // round-to-nearest-even
    return (u16)(u >> 16);
}
__device__ __forceinline__ float gelu_exact(float v) {
    return 0.5f * v * (1.0f + erff(v * 0.70710678118654752f));
}

// ---------------- weight split+transpose: W[K][N] fp32 -> Wt_hi/lo [N][K] bf16 ----------
__global__ __launch_bounds__(256)
void wsplit_kernel(const float* __restrict__ q, const float* __restrict__ qcut,
                   const float* __restrict__ a, const float* __restrict__ l,
                   const float* __restrict__ kv, const float* __restrict__ efo,
                   const float* __restrict__ eba, const float* __restrict__ proj,
                   const float* __restrict__ proje,
                   u16* __restrict__ dh, u16* __restrict__ dl)
{
    int e = blockIdx.x * 256 + threadIdx.x;    // 524288 total
    const float* src; int N, base, le;
    if (e < 65536)       { src = q;     N = 256; base = 0;      le = e; }
    else if (e < 98304)  { src = qcut;  N = 128; base = 65536;  le = e - 65536; }
    else if (e < 163840) { src = a;     N = 256; base = 98304;  le = e - 98304; }
    else if (e < 229376) { src = l;     N = 256; base = 163840; le = e - 163840; }
    else if (e < 294912) { src = kv;    N = 256; base = 229376; le = e - 229376; }
    else if (e < 311296) { src = efo;   N = 128; base = 294912; le = e - 294912; }
    else if (e < 327680) { src = eba;   N = 128; base = 311296; le = e - 311296; }
    else if (e < 458752) { src = proj;  N = 256; base = 327680; le = e - 327680; }
    else                 { src = proje; N = 128; base = 458752; le = e - 458752; }
    int K = (base >= 327680) ? 512 : ((base >= 294912) ? 128 : 256);
    int k = le / N, n = le & (N - 1);
    float w = src[le];
    u16 h = f2bf(w);
    dh[base + n * K + k] = h;
    dl[base + n * K + k] = f2bf(w - bf2f(h));
}

// ---------------- conv weight transpose: [C][49] -> [49][C] fp32 ----------------
__global__ __launch_bounds__(256)
void cwt_kernel(const float* __restrict__ conv_w, const float* __restrict__ econv_w,
                float* __restrict__ wt)
{
    int i = blockIdx.x * 256 + threadIdx.x;
    if (i < 12544) {                    // 256*49
        int c = i / 49, tap = i % 49;
        wt[tap * 256 + c] = conv_w[i];
    } else if (i < 18816) {             // + 128*49
        int j = i - 12544;
        int c = j / 49, tap = j % 49;
        wt[12544 + tap * 128 + c] = econv_w[j];
    }
}

// ---------------- LayerNorm: fp32 in -> bf16 hi/lo out ----------------
template<int CH>
__global__ __launch_bounds__(256)
void ln_kernel(const float* __restrict__ x, const float* __restrict__ w,
               const float* __restrict__ b, u16* __restrict__ oh, u16* __restrict__ ol)
{
    const int lane = threadIdx.x & 63;
    const int wv = threadIdx.x >> 6;
    const size_t tok = (size_t)blockIdx.x * 4 + wv;
    constexpr int V = CH / 64;
    float v[V];
    float s = 0.f, sq = 0.f;
    if constexpr (CH == 256) {
        float4 t4 = *(const float4*)(x + tok * CH + lane * 4);
        v[0] = t4.x; v[1] = t4.y; v[2] = t4.z; v[3] = t4.w;
    } else {
        float2 t2 = *(const float2*)(x + tok * CH + lane * 2);
        v[0] = t2.x; v[1] = t2.y;
    }
    #pragma unroll
    for (int i = 0; i < V; ++i) { s += v[i]; sq += v[i] * v[i]; }
    #pragma unroll
    for (int off = 32; off > 0; off >>= 1) {
        s += __shfl_xor(s, off);
        sq += __shfl_xor(sq, off);
    }
    const float mean = s * (1.0f / CH);
    const float var = sq * (1.0f / CH) - mean * mean;
    const float rstd = rsqrtf(var + 1e-6f);
    u16 hh[V], ll[V];
    #pragma unroll
    for (int i = 0; i < V; ++i) {
        float o = (v[i] - mean) * rstd * w[lane * V + i] + b[lane * V + i];
        hh[i] = f2bf(o);
        ll[i] = f2bf(o - bf2f(hh[i]));
    }
    if constexpr (CH == 256) {
        ushort4 th = {hh[0], hh[1], hh[2], hh[3]};
        ushort4 tl = {ll[0], ll[1], ll[2], ll[3]};
        *(ushort4*)(oh + tok * CH + lane * 4) = th;
        *(ushort4*)(ol + tok * CH + lane * 4) = tl;
    } else {
        ushort2 th = {hh[0], hh[1]};
        ushort2 tl = {ll[0], ll[1]};
        *(ushort2*)(oh + tok * CH + lane * 2) = th;
        *(ushort2*)(ol + tok * CH + lane * 2) = tl;
    }
}

// ---------------- AdaptiveAvgPool(7,7) over concat(xn,xen) + scl linear (fp32 out) ------
__global__ __launch_bounds__(128)
void pool_scl_kernel(const u16* __restrict__ xnh, const u16* __restrict__ xnl,
                     const u16* __restrict__ xeh, const u16* __restrict__ xel,
                     const float* __restrict__ sclw, const float* __restrict__ sclb,
                     float* __restrict__ m)
{
    __shared__ float pooled[384];
    const int bp = blockIdx.x;           // b*49 + p
    const int b = bp / 49, p = bp % 49;
    const int py = p / 7, px = p % 7;
    const int tid = threadIdx.x;         // 128
    for (int ch = tid; ch < 384; ch += 128) {
        float acc = 0.f;
        for (int i = 0; i < 96; ++i) {
            int y = py * 8 + i / 12, x = px * 12 + i % 12;
            size_t pix = ((size_t)(b * HDIM + y) * WDIM + x);
            if (ch < 256) acc += bf2f(xnh[pix * 256 + ch]) + bf2f(xnl[pix * 256 + ch]);
            else          acc += bf2f(xeh[pix * 128 + ch - 256]) + bf2f(xel[pix * 128 + ch - 256]);
        }
        pooled[ch] = acc * (1.0f / 96.0f);
    }
    __syncthreads();
    float acc = sclb[tid];
    for (int k = 0; k < 384; ++k) acc = fmaf(pooled[k], sclw[k * 128 + tid], acc);
    m[(size_t)bp * 128 + tid] = acc;
}

// ---------------- MFMA bf16x3 GEMM ------------------------------------------------------
// A: ASRC=0 -> [M][K] hi/lo bf16 pair (Ah,Al); ASRC=1 -> [M][K] fp32 (Af), split in staging.
// B: PRE-TRANSPOSED [N][K] hi/lo bf16 (wsplit output).
// EPI: 0 = store pair; 1 = gelu + store fp32 Df; 2 = multiply existing pair, store pair;
//      3 = store fp32 Df.
#define BK 32
#define PADK 40
template<int EPI, int ASRC>
__global__ __launch_bounds__(256, 2)
void mgemm(const u16* __restrict__ Ah, const u16* __restrict__ Al,
           const float* __restrict__ Af, int lda,
           const u16* __restrict__ Bh, const u16* __restrict__ Bl, int K,
           const float* __restrict__ bias,
           u16* __restrict__ Dh, u16* __restrict__ Dl,
           float* __restrict__ Df, int ldd)
{
    __shared__ u16 AsH[128 * PADK], AsL[128 * PADK], BsH[128 * PADK], BsL[128 * PADK];
    const int t = threadIdx.x;
    const int m0 = blockIdx.x * 128, n0 = blockIdx.y * 128;
    const int sr = t >> 1;               // staging row 0..127
    const int sk = (t & 1) * 16;         // staging k-offset
    const int lane = t & 63;
    const int w = t >> 6;
    const int wm = w >> 1, wn = w & 1;   // wave 2x2 grid, each 64x64
    const int frow = lane & 15;
    const int fko = (lane >> 4) * 8;

    const u16* pBh = Bh + (size_t)(n0 + sr) * K + sk;
    const u16* pBl = Bl + (size_t)(n0 + sr) * K + sk;
    int4 rBh0 = *(const int4*)(pBh);     int4 rBh1 = *(const int4*)(pBh + 8);
    int4 rBl0 = *(const int4*)(pBl);     int4 rBl1 = *(const int4*)(pBl + 8);

    const u16* pAh = nullptr; const u16* pAl = nullptr; const float* pAf = nullptr;
    int4 rAh0, rAh1, rAl0, rAl1;
    float4 rf0, rf1, rf2, rf3;
    if constexpr (ASRC == 0) {
        pAh = Ah + (size_t)(m0 + sr) * lda + sk;
        pAl = Al + (size_t)(m0 + sr) * lda + sk;
        rAh0 = *(const int4*)(pAh);  rAh1 = *(const int4*)(pAh + 8);
        rAl0 = *(const int4*)(pAl);  rAl1 = *(const int4*)(pAl + 8);
    } else {
        pAf = Af + (size_t)(m0 + sr) * lda + sk;
        rf0 = *(const float4*)(pAf);      rf1 = *(const float4*)(pAf + 4);
        rf2 = *(const float4*)(pAf + 8);  rf3 = *(const float4*)(pAf + 12);
    }

    floatx4 acc[4][4] = {};

    for (int k0 = 0; k0 < K; k0 += BK) {
        __syncthreads();
        if constexpr (ASRC == 0) {
            *(int4*)&AsH[sr * PADK + sk] = rAh0;  *(int4*)&AsH[sr * PADK + sk + 8] = rAh1;
            *(int4*)&AsL[sr * PADK + sk] = rAl0;  *(int4*)&AsL[sr * PADK + sk + 8] = rAl1;
        } else {
            float fv[16] = {rf0.x, rf0.y, rf0.z, rf0.w, rf1.x, rf1.y, rf1.z, rf1.w,
                            rf2.x, rf2.y, rf2.z, rf2.w, rf3.x, rf3.y, rf3.z, rf3.w};
            ushort8 h0, h1, l0, l1;
            #pragma unroll
            for (int j = 0; j < 8; ++j) {
                unsigned ua = __builtin_bit_cast(unsigned, fv[j]);
                u16 ha = (u16)(ua >> 16);                 // truncated hi
                h0[j] = ha;
                l0[j] = f2bf(fv[j] - bf2f(ha));
                unsigned ub = __builtin_bit_cast(unsigned, fv[j + 8]);
                u16 hb = (u16)(ub >> 16);
                h1[j] = hb;
                l1[j] = f2bf(fv[j + 8] - bf2f(hb));
            }
            *(ushort8*)&AsH[sr * PADK + sk] = h0;  *(ushort8*)&AsH[sr * PADK + sk + 8] = h1;
            *(ushort8*)&AsL[sr * PADK + sk] = l0;  *(ushort8*)&AsL[sr * PADK + sk + 8] = l1;
        }
        *(int4*)&BsH[sr * PADK + sk] = rBh0;  *(int4*)&BsH[sr * PADK + sk + 8] = rBh1;
        *(int4*)&BsL[sr * PADK + sk] = rBl0;  *(int4*)&BsL[sr * PADK + sk + 8] = rBl1;
        __syncthreads();
        if (k0 + BK < K) {
            if constexpr (ASRC == 0) {
                rAh0 = *(const int4*)(pAh + k0 + BK);  rAh1 = *(const int4*)(pAh + k0 + BK + 8);
                rAl0 = *(const int4*)(pAl + k0 + BK);  rAl1 = *(const int4*)(pAl + k0 + BK + 8);
            } else {
                rf0 = *(const float4*)(pAf + k0 + BK);      rf1 = *(const float4*)(pAf + k0 + BK + 4);
                rf2 = *(const float4*)(pAf + k0 + BK + 8);  rf3 = *(const float4*)(pAf + k0 + BK + 12);
            }
            rBh0 = *(const int4*)(pBh + (size_t)(k0 + BK));  rBh1 = *(const int4*)(pBh + (size_t)(k0 + BK) + 8);
            rBl0 = *(const int4*)(pBl + (size_t)(k0 + BK));  rBl1 = *(const int4*)(pBl + (size_t)(k0 + BK) + 8);
        }
        short8 afh[4], afl[4], bfh[4], bfl[4];
        #pragma unroll
        for (int i = 0; i < 4; ++i) {
            int ar = wm * 64 + i * 16 + frow;
            afh[i] = *(const short8*)&AsH[ar * PADK + fko];
            afl[i] = *(const short8*)&AsL[ar * PADK + fko];
            int bc = wn * 64 + i * 16 + frow;
            bfh[i] = *(const short8*)&BsH[bc * PADK + fko];
            bfl[i] = *(const short8*)&BsL[bc * PADK + fko];
        }
        #pragma unroll
        for (int mt = 0; mt < 4; ++mt)
        #pragma unroll
        for (int nt = 0; nt < 4; ++nt) {
            acc[mt][nt] = __builtin_amdgcn_mfma_f32_16x16x32_bf16(afh[mt], bfh[nt], acc[mt][nt], 0, 0, 0);
            acc[mt][nt] = __builtin_amdgcn_mfma_f32_16x16x32_bf16(afh[mt], bfl[nt], acc[mt][nt], 0, 0, 0);
            acc[mt][nt] = __builtin_amdgcn_mfma_f32_16x16x32_bf16(afl[mt], bfh[nt], acc[mt][nt], 0, 0, 0);
        }
    }

    // epilogue: C/D layout col = lane&15, row = (lane>>4)*4 + i  [m89-verified]
    #pragma unroll
    for (int mt = 0; mt < 4; ++mt)
    #pragma unroll
    for (int nt = 0; nt < 4; ++nt)
    #pragma unroll
    for (int i = 0; i < 4; ++i) {
        int r = m0 + wm * 64 + mt * 16 + (lane >> 4) * 4 + i;
        int c = n0 + wn * 64 + nt * 16 + (lane & 15);
        float v = acc[mt][nt][i] + bias[c];
        size_t off = (size_t)r * ldd + c;
        if constexpr (EPI == 1) {
            Df[off] = gelu_exact(v);
        } else if constexpr (EPI == 3) {
            Df[off] = v;
        } else {
            if constexpr (EPI == 2) v *= bf2f(Dh[off]) + bf2f(Dl[off]);
            u16 h = f2bf(v);
            Dh[off] = h;
            Dl[off] = f2bf(v - bf2f(h));
        }
    }
}

// ---------------- Depthwise 7x7 conv, channels-last, zero pad 3 -------------------------
// fp32 input (no decode), bf16-pair output. Thread = (x, 4-row strip, 8 channels).
// Weights from pre-transposed wT[tap][C] fp32 (L1/L2-resident). Tap index r-s is
// compile-time after unroll.
template<int C>
__global__ __launch_bounds__(256)
void dwconv7_kernel(const float* __restrict__ in, const float* __restrict__ wT,
                    const float* __restrict__ bias,
                    u16* __restrict__ outh, u16* __restrict__ outl)
{
    constexpr int CPW = C / 8;
    const int gid = blockIdx.x * 256 + threadIdx.x;   // over B*(H/4)*W*CPW
    const int cw = gid % CPW;
    const int c = cw * 8;
    int t2 = gid / CPW;
    const int x = t2 % WDIM;
    int t3 = t2 / WDIM;
    const int ys = t3 % (HDIM / 4);
    const int b = t3 / (HDIM / 4);
    const int y0 = ys * 4;
    float acc[4][8];
    {
        float4 b0 = *(const float4*)(bias + c);
        float4 b1 = *(const float4*)(bias + c + 4);
        #pragma unroll
        for (int s = 0; s < 4; ++s) {
            acc[s][0] = b0.x; acc[s][1] = b0.y; acc[s][2] = b0.z; acc[s][3] = b0.w;
            acc[s][4] = b1.x; acc[s][5] = b1.y; acc[s][6] = b1.z; acc[s][7] = b1.w;
        }
    }
    #pragma unroll
    for (int r = 0; r < 10; ++r) {
        int yy = y0 + r - 3;
        if (yy < 0 || yy >= HDIM) continue;
        #pragma unroll
        for (int kx = 0; kx < 7; ++kx) {
            int xx = x + kx - 3;
            if (xx < 0 || xx >= WDIM) continue;
            const float* ip = in + ((size_t)((b * HDIM + yy) * WDIM + xx)) * C + c;
            float4 i0 = *(const float4*)ip;
            float4 i1 = *(const float4*)(ip + 4);
            float iv[8] = {i0.x, i0.y, i0.z, i0.w, i1.x, i1.y, i1.z, i1.w};
            #pragma unroll
            for (int s = 0; s < 4; ++s) {
                if (r - s < 0 || r - s > 6) continue;   // compile-time after unroll
                const float* wp = wT + ((r - s) * 7 + kx) * C + c;
                float4 w0 = *(const float4*)wp;
                float4 w1 = *(const float4*)(wp + 4);
                float wv[8] = {w0.x, w0.y, w0.z, w0.w, w1.x, w1.y, w1.z, w1.w};
                #pragma unroll
                for (int j = 0; j < 8; ++j)
                    acc[s][j] = fmaf(iv[j], wv[j], acc[s][j]);
            }
        }
    }
    #pragma unroll
    for (int s = 0; s < 4; ++s) {
        size_t pix = (size_t)((b * HDIM + y0 + s) * WDIM + x);
        ushort8 oh, ol;
        #pragma unroll
        for (int j = 0; j < 8; ++j) {
            u16 h = f2bf(acc[s][j]);
            oh[j] = h;
            ol[j] = f2bf(acc[s][j] - bf2f(h));
        }
        *(ushort8*)(outh + pix * C + c) = oh;
        *(ushort8*)(outl + pix * C + c) = ol;
    }
}

// ---------------- Split-KV fused attention, partial pass ----------------
__global__ __launch_bounds__(256)
void attn_part_kernel(const float* __restrict__ m, const u16* __restrict__ kvh,
                      const u16* __restrict__ kvl,
                      float* __restrict__ Opart, float* __restrict__ mpart,
                      float* __restrict__ lpart)
{
    __shared__ float mq[NQ * 17];
    __shared__ float Ks[TSUB * 16];
    __shared__ float Vs[TSUB * 16];
    __shared__ float St[NQ * 85];
    __shared__ float Osm[NQ * 16];
    __shared__ float rowm[NQ], rowl[NQ], rowscale[NQ], rownewm[NQ];
    const int blk = blockIdx.x;
    const int bh = blk >> 3, s = blk & 7;
    const int b = bh >> 3, h = bh & 7;
    const int tid = threadIdx.x;
    const int tbase = s * TOKSPL;
    for (int i = tid; i < NQ * 16; i += 256) {
        int p = i >> 4, d = i & 15;
        mq[p * 17 + d] = m[((size_t)(b * 49 + p)) * 128 + h * 16 + d] * 0.25f;
        Osm[i] = 0.f;
    }
    if (tid < NQ) { rowm[tid] = -3.4e38f; rowl[tid] = 0.f; }
    __syncthreads();
    for (int c0 = 0; c0 < TOKSPL; c0 += TSUB) {
        const int t0 = tbase + c0;
        for (int i = tid; i < TSUB * 4; i += 256) {
            int row = i >> 2, q = (i & 3) << 2;
            size_t base = ((size_t)(b * HWTOK + t0 + row)) * 256 + h * 16 + q;
            ushort4 kh = *(const ushort4*)(kvh + base);
            ushort4 kl = *(const ushort4*)(kvl + base);
            ushort4 vh = *(const ushort4*)(kvh + base + 128);
            ushort4 vl = *(const ushort4*)(kvl + base + 128);
            Ks[row * 16 + q + 0] = bf2f(kh.x) + bf2f(kl.x);
            Ks[row * 16 + q + 1] = bf2f(kh.y) + bf2f(kl.y);
            Ks[row * 16 + q + 2] = bf2f(kh.z) + bf2f(kl.z);
            Ks[row * 16 + q + 3] = bf2f(kh.w) + bf2f(kl.w);
            Vs[row * 16 + q + 0] = bf2f(vh.x) + bf2f(vl.x);
            Vs[row * 16 + q + 1] = bf2f(vh.y) + bf2f(vl.y);
            Vs[row * 16 + q + 2] = bf2f(vh.z) + bf2f(vl.z);
            Vs[row * 16 + q + 3] = bf2f(vh.w) + bf2f(vl.w);
        }
        __syncthreads();
        for (int i = tid; i < NQ * TSUB; i += 256) {
            int p = i % NQ, t = i / NQ;
            const float* mp = &mq[p * 17];
            const float* kp = &Ks[t * 16];
            float sv = 0.f;
            #pragma unroll
            for (int d = 0; d < 16; ++d) sv = fmaf(mp[d], kp[d], sv);
            St[p * 85 + t] = sv;
        }
        __syncthreads();
        if (tid < NQ) {
            float mx = -3.4e38f;
            const float* sr = &St[tid * 85];
            for (int t = 0; t < TSUB; ++t) mx = fmaxf(mx, sr[t]);
            float nm = fmaxf(rowm[tid], mx);
            rownewm[tid] = nm;
            rowscale[tid] = expf(rowm[tid] - nm);
        }
        __syncthreads();
        for (int i = tid; i < NQ * TSUB; i += 256) {
            int p = i / TSUB, t = i % TSUB;
            St[p * 85 + t] = expf(St[p * 85 + t] - rownewm[p]);
        }
        __syncthreads();
        if (tid < NQ) {
            float sv = 0.f;
            const float* sr = &St[tid * 85];
            for (int t = 0; t < TSUB; ++t) sv += sr[t];
            rowl[tid] = rowl[tid] * rowscale[tid] + sv;
            rowm[tid] = rownewm[tid];
        }
        for (int i = tid; i < NQ * 16; i += 256) {
            int p = i >> 4, d = i & 15;
            float acc = Osm[i] * rowscale[p];
            const float* sr = &St[p * 85];
            const float* vp = &Vs[d];
            #pragma unroll 6
            for (int t = 0; t < TSUB; ++t) acc = fmaf(sr[t], vp[t * 16], acc);
            Osm[i] = acc;
        }
        __syncthreads();
    }
    for (int i = tid; i < NQ * 16; i += 256)
        Opart[(size_t)blk * (NQ * 16) + i] = Osm[i];
    if (tid < NQ) {
        mpart[blk * NQ + tid] = rowm[tid];
        lpart[blk * NQ + tid] = rowl[tid];
    }
}

// ---------------- combine 8 split partials -> ao ----------------
__global__ __launch_bounds__(256)
void attn_combine_kernel(const float* __restrict__ Opart, const float* __restrict__ mpart,
                         const float* __restrict__ lpart, float* __restrict__ ao)
{
    const int bh = blockIdx.x;
    const int b = bh >> 3, h = bh & 7;
    const int tid = threadIdx.x;
    for (int i = tid; i < NQ * 16; i += 256) {
        int p = i >> 4, d = i & 15;
        float M = -3.4e38f;
        #pragma unroll
        for (int s = 0; s < SPLIT; ++s)
            M = fmaxf(M, mpart[(bh * SPLIT + s) * NQ + p]);
        float sO = 0.f, sl = 0.f;
        #pragma unroll
        for (int s = 0; s < SPLIT; ++s) {
            float e = expf(mpart[(bh * SPLIT + s) * NQ + p] - M);
            sl = fmaf(lpart[(bh * SPLIT + s) * NQ + p], e, sl);
            sO = fmaf(Opart[(size_t)(bh * SPLIT + s) * (NQ * 16) + i], e, sO);
        }
        ao[((size_t)(b * 49 + p)) * 128 + h * 16 + d] = sO / sl;
    }
}

// ---------------- bilinear 7x7 -> 56x84, writes cat bf16-pair cols 256..383 -------------
__global__ __launch_bounds__(256)
void resize_kernel(const float* __restrict__ ao, u16* __restrict__ cath,
                   u16* __restrict__ catl)
{
    const int idx = blockIdx.x * 256 + threadIdx.x;   // over N*128
    const int c = idx & 127;
    const int p = idx >> 7;
    const int x = p % WDIM;
    int tmp = p / WDIM;
    const int y = tmp % HDIM;
    const int b = tmp / HDIM;
    float fy = (y + 0.5f) * 0.125f - 0.5f;
    float fx = (x + 0.5f) * (1.0f / 12.0f) - 0.5f;
    float yf = floorf(fy), xf = floorf(fx);
    int y0 = (int)yf, x0 = (int)xf;
    float wy = fy - yf, wx = fx - xf;
    int y1 = y0 + 1 < 6 ? y0 + 1 : 6;
    int x1 = x0 + 1 < 6 ? x0 + 1 : 6;
    y0 = y0 > 0 ? y0 : 0;
    x0 = x0 > 0 ? x0 : 0;
    const float* base = ao + (size_t)b * 49 * 128 + c;
    float v00 = base[(y0 * 7 + x0) * 128], v01 = base[(y0 * 7 + x1) * 128];
    float v10 = base[(y1 * 7 + x0) * 128], v11 = base[(y1 * 7 + x1) * 128];
    float r = (1.f - wy) * ((1.f - wx) * v00 + wx * v01)
            + wy * ((1.f - wx) * v10 + wx * v11);
    u16 h = f2bf(r);
    cath[(size_t)p * 512 + 256 + c] = h;
    catl[(size_t)p * 512 + 256 + c] = f2bf(r - bf2f(h));
}

extern "C" void kernel_launch(void* const* d_in, const int* in_sizes, int n_in,
                              void* d_out, int out_size, void* d_ws, size_t ws_size,
                              hipStream_t stream) {
    const float* x       = (const float*)d_in[0];
    const float* x_e     = (const float*)d_in[1];
    const float* ln_w    = (const float*)d_in[2];
    const float* ln_b    = (const float*)d_in[3];
    const float* lne_w   = (const float*)d_in[4];
    const float* lne_b   = (const float*)d_in[5];
    const float* q_w     = (const float*)d_in[6];
    const float* q_b     = (const float*)d_in[7];
    const float* qcut_w  = (const float*)d_in[8];
    const float* qcut_b  = (const float*)d_in[9];
    const float* a_w     = (const float*)d_in[10];
    const float* a_b     = (const float*)d_in[11];
    const float* l_w     = (const float*)d_in[12];
    const float* l_b     = (const float*)d_in[13];
    const float* conv_w  = (const float*)d_in[14];
    const float* conv_b  = (const float*)d_in[15];
    const float* econv_w = (const float*)d_in[16];
    const float* econv_b = (const float*)d_in[17];
    const float* efore_w = (const float*)d_in[18];
    const float* efore_b = (const float*)d_in[19];
    const float* eback_w = (const float*)d_in[20];
    const float* eback_b = (const float*)d_in[21];
    const float* kv_w    = (const float*)d_in[22];
    const float* kv_b    = (const float*)d_in[23];
    const float* scl_w   = (const float*)d_in[24];
    const float* scl_b   = (const float*)d_in[25];
    const float* proj_w  = (const float*)d_in[26];
    const float* proj_b  = (const float*)d_in[27];
    const float* proje_w = (const float*)d_in[28];
    const float* proje_b = (const float*)d_in[29];

    float* out_x = (float*)d_out;                   // (N,256) fp32
    float* out_e = out_x + (size_t)N_TOK * 256;     // (N,128) fp32

    const size_t NT = N_TOK;

    // d_out doubles as scratch (exact fit):
    //   xlF  (NT*256 f32) = out_x region; after kv-GEMM dead:
    //     e1F (NT*128 f32) first half; e2 pair (NT*128 u16 x2) second half
    //   xen pair (NT*256 u16) = out_e region
    float* xlF  = (float*)d_out;
    float* e1F  = xlF;                         // NT*128 f32
    u16*   e2H  = (u16*)(xlF + NT * 128);      // NT*128 u16
    u16*   e2L  = e2H + NT * 128;              // NT*128 u16
    u16*   xenH = (u16*)(xlF + NT * 256);      // out_e region
    u16*   xenL = xenH + NT * 128;

    // Workspace (~238 MB):
    u16* ws   = (u16*)d_ws;
    u16* xnH  = ws;                    // NT*256  xn -> conv_out -> kv
    u16* xnL  = xnH  + NT * 256;
    u16* catH = xnL  + NT * 256;       // NT*512
    u16* catL = catH + NT * 512;
    u16* wtH  = catL + NT * 512;       // 524288 split weights (transposed [N][K])
    u16* wtL  = wtH  + 524288;
    float* mbuf  = (float*)(wtL + 524288); // 16*49*128 fp32
    float* aosm  = mbuf + 16 * 49 * 128;   // 16*49*128 fp32
    float* Opart = aosm + 16 * 49 * 128;   // 1024*784 fp32
    float* mpart = Opart + 1024 * NQ * 16; // 1024*49
    float* lpart = mpart + 1024 * NQ;      // 1024*49
    float* cwT   = lpart + 1024 * NQ;      // 49*256 + 49*128 fp32 transposed conv weights
    float* ecwT  = cwT + 12544;

    // split-weight offsets (must match wsplit_kernel)
    u16 *qtH = wtH + 0,      *qtL = wtL + 0;
    u16 *qctH = wtH + 65536, *qctL = wtL + 65536;
    u16 *atH = wtH + 98304,  *atL = wtL + 98304;
    u16 *ltH = wtH + 163840, *ltL = wtL + 163840;
    u16 *kvtH = wtH + 229376,*kvtL = wtL + 229376;
    u16 *efH = wtH + 294912, *efL = wtL + 294912;
    u16 *ebH = wtH + 311296, *ebL = wtL + 311296;
    u16 *pjH = wtH + 327680, *pjL = wtL + 327680;
    u16 *peH = wtH + 458752, *peL = wtL + 458752;

    // aliases
    u16 *cvH = xnH, *cvL = xnL;        // conv output (after xn dead)
    u16 *kvH = xnH, *kvL = xnL;        // kv (after conv_out dead)

    dim3 g2(588, 2), g1(588, 1);

    wsplit_kernel<<<2048, 256, 0, stream>>>(q_w, qcut_w, a_w, l_w, kv_w, efore_w,
                                            eback_w, proj_w, proje_w, wtH, wtL);
    cwt_kernel<<<74, 256, 0, stream>>>(conv_w, econv_w, cwT);

    ln_kernel<256><<<N_TOK / 4, 256, 0, stream>>>(x, ln_w, ln_b, xnH, xnL);
    ln_kernel<128><<<N_TOK / 4, 256, 0, stream>>>(x_e, lne_w, lne_b, xenH, xenL);
    pool_scl_kernel<<<16 * 49, 128, 0, stream>>>(xnH, xnL, xenH, xenL, scl_w, scl_b, mbuf);

    mgemm<0, 0><<<g2, 256, 0, stream>>>(xnH, xnL, nullptr, 256, qtH, qtL, 256, q_b,
                                        catH, catL, nullptr, 512);
    mgemm<0, 0><<<g1, 256, 0, stream>>>(xnH, xnL, nullptr, 256, qctH, qctL, 256, qcut_b,
                                        catH + 384, catL + 384, nullptr, 512);
    mgemm<1, 0><<<g2, 256, 0, stream>>>(xnH, xnL, nullptr, 256, ltH, ltL, 256, l_b,
                                        nullptr, nullptr, xlF, 256);
    // xn dead
    dwconv7_kernel<256><<<(N_TOK / 4) * 32 / 256, 256, 0, stream>>>(xlF, cwT, conv_b, cvH, cvL);
    mgemm<2, 0><<<g2, 256, 0, stream>>>(cvH, cvL, nullptr, 256, atH, atL, 256, a_b,
                                        catH, catL, nullptr, 512);
    // conv_out dead
    mgemm<0, 1><<<g2, 256, 0, stream>>>(nullptr, nullptr, xlF, 256, kvtH, kvtL, 256, kv_b,
                                        kvH, kvL, nullptr, 256);
    // xlF dead -> region hosts e1F / e2 pair
    attn_part_kernel<<<BDIM * NHEAD * SPLIT, 256, 0, stream>>>(mbuf, kvH, kvL,
                                                               Opart, mpart, lpart);
    attn_combine_kernel<<<BDIM * NHEAD, 256, 0, stream>>>(Opart, mpart, lpart, aosm);
    resize_kernel<<<(N_TOK * 128) / 256, 256, 0, stream>>>(aosm, catH, catL);

    mgemm<3, 0><<<g1, 256, 0, stream>>>(xenH, xenL, nullptr, 128, efH, efL, 128, efore_b,
                                        nullptr, nullptr, e1F, 128);
    dwconv7_kernel<128><<<(N_TOK / 4) * 16 / 256, 256, 0, stream>>>(e1F, ecwT, econv_b, e2H, e2L);
    mgemm<2, 0><<<g1, 256, 0, stream>>>(e2H, e2L, nullptr, 128, ebH, ebL, 128, eback_b,
                                        catH + 384, catL + 384, nullptr, 512);
    // xen + e1/e2 dead; proj/proje overwrite d_out fully
    mgemm<3, 0><<<g2, 256, 0, stream>>>(catH, catL, nullptr, 512, pjH, pjL, 512, proj_b,
                                        nullptr, nullptr, out_x, 256);
    mgemm<3, 0><<<g1, 256, 0, stream>>>(catH, catL, nullptr, 512, peH, peL, 512, proje_b,
                                        nullptr, nullptr, out_e, 128);
}